// Round 11
// baseline (997.639 us; speedup 1.0000x reference)
//
#include <hip/hip_runtime.h>
#include <hip/hip_fp16.h>
#include <stdint.h>

#define N_NODES 100000
#define N_EDGES 3200000
#define BN      64                    // nodes per dst-bucket
#define NB      1563                  // ceil(N_NODES / BN)
// histogram granularity (fine)
#define NCH_H   1024
#define CH_H    (N_EDGES / NCH_H)     // 3125
#define CPL     (NCH_H / 64)          // 16 chunks per lane in chunkscan
#define PAD_PER 98                    // nodes padded per hist block
// scatter granularity (coarse, for long coalesced runs)
#define NCH_S   256
#define CH_S    (N_EDGES / NCH_S)     // 12500
#define BS1     1024                  // scatter1 block size
#define S1_IT   ((CH_S + BS1 - 1) / BS1)
#define S2_CAP  2560                  // scatter2 LDS stage capacity
#define BLOCK   256
#define PGRID   512                   // persistent kernel: 2 blocks/CU guaranteed
#define W_SCALE 32767.0f
#define W_INV   (1.0f / 32767.0f)

// ---------------------------------------------------------------------------
// Stage 1: per-subchunk bucket histogram + fused x->fp16 padding
// ---------------------------------------------------------------------------
__global__ void hist_kernel(const int* __restrict__ dst, int* __restrict__ hist_g,
                            const float* __restrict__ x, __half* __restrict__ xpad) {
    __shared__ int h[NB];
    for (int b = threadIdx.x; b < NB; b += BLOCK) h[b] = 0;
    {
        int i = blockIdx.x * PAD_PER + threadIdx.x;
        if (threadIdx.x < PAD_PER && i < N_NODES) {
            const float* xr = x + (size_t)i * 6;
            __half2 hh[4];
            hh[0] = __halves2half2(__float2half(xr[0]), __float2half(xr[1]));
            hh[1] = __halves2half2(__float2half(xr[2]), __float2half(xr[3]));
            hh[2] = __halves2half2(__float2half(xr[4]), __float2half(xr[5]));
            hh[3] = __halves2half2(__float2half(0.f),   __float2half(0.f));
            *(uint4*)(xpad + (size_t)i * 8) = *(uint4*)hh;
        }
    }
    __syncthreads();
    const int c  = blockIdx.x;
    const int k0 = c * CH_H;
    for (int k = threadIdx.x; k < CH_H; k += BLOCK)
        atomicAdd(&h[dst[k0 + k] >> 6], 1);
    __syncthreads();
    for (int b = threadIdx.x; b < NB; b += BLOCK)
        hist_g[c * NB + b] = h[b];
}

// ---------------------------------------------------------------------------
// Stage 2a: per-bucket exclusive scan over the 1024 subchunk counts
// ---------------------------------------------------------------------------
__global__ void chunkscan_kernel(const int* __restrict__ hist_g,
                                 int* __restrict__ off_g, int* __restrict__ tot) {
    int w    = (blockIdx.x * blockDim.x + threadIdx.x) >> 6;
    int lane = threadIdx.x & 63;
    if (w >= NB) return;
    int v[CPL];
    int ls = 0;
    const int cbase = lane * CPL;
    #pragma unroll
    for (int i = 0; i < CPL; ++i) { v[i] = hist_g[(cbase + i) * NB + w]; ls += v[i]; }
    int run = ls;
    #pragma unroll
    for (int d = 1; d < 64; d <<= 1) {
        int u = __shfl_up(run, d);
        if (lane >= d) run += u;
    }
    int acc = run - ls;
    #pragma unroll
    for (int i = 0; i < CPL; ++i) { off_g[(cbase + i) * NB + w] = acc; acc += v[i]; }
    if (lane == 63) tot[w] = acc;
}

// ---------------------------------------------------------------------------
// Stage 2b: exclusive scan of 1563 bucket totals (one wg)
// ---------------------------------------------------------------------------
#define SCAN_T   1024
#define SCAN_PER 2
__global__ void scan_kernel(const int* __restrict__ cnt, int* __restrict__ bstart) {
    __shared__ int part[SCAN_T];
    int t = threadIdx.x;
    int local[SCAN_PER];
    int s = 0;
    #pragma unroll
    for (int i = 0; i < SCAN_PER; ++i) {
        int idx = t * SCAN_PER + i;
        int v = (idx < NB) ? cnt[idx] : 0;
        local[i] = s;
        s += v;
    }
    part[t] = s;
    __syncthreads();
    for (int off = 1; off < SCAN_T; off <<= 1) {
        int v = (t >= off) ? part[t - off] : 0;
        __syncthreads();
        part[t] += v;
        __syncthreads();
    }
    int excl = part[t] - s;
    #pragma unroll
    for (int i = 0; i < SCAN_PER; ++i) {
        int idx = t * SCAN_PER + i;
        if (idx < NB) bstart[idx] = excl + local[i];
    }
}

// ---------------------------------------------------------------------------
// Stage 3: scatter pass 1, stage-and-flush (8 B records, proven R7/R9 config).
// rec1: x = src(17) | dl(6)<<17 ; y = weight fp32 bits.
// ---------------------------------------------------------------------------
__global__ void __launch_bounds__(BS1)
scatter1_kernel(const int* __restrict__ src, const int* __restrict__ dst,
                const float* __restrict__ w,
                const int* __restrict__ bstart, const int* __restrict__ off_g,
                uint2* __restrict__ rec1) {
    __shared__ uint32_t stage[CH_S];   // 50000 B
    __shared__ int h[NB];
    __shared__ int delta[NB];
    __shared__ int wtot[BS1 / 64];

    const int c  = blockIdx.x;
    const int k0 = c * CH_S;
    const int t  = threadIdx.x;

    for (int b = t; b < NB; b += BS1) h[b] = 0;
    __syncthreads();
    int dstv[S1_IT];
    int nit = 0;
    for (int k = t; k < CH_S; k += BS1, ++nit) {
        int d = dst[k0 + k];
        dstv[nit] = d;
        atomicAdd(&h[d >> 6], 1);
    }
    __syncthreads();

    {
        const int base = t * 2;          // 2048 >= NB
        int v[2], ls = 0;
        #pragma unroll
        for (int i = 0; i < 2; ++i) {
            int idx = base + i;
            v[i] = (idx < NB) ? h[idx] : 0;
            ls += v[i];
        }
        int lane = t & 63, wv = t >> 6;
        int run = ls;
        #pragma unroll
        for (int d = 1; d < 64; d <<= 1) {
            int u = __shfl_up(run, d);
            if (lane >= d) run += u;
        }
        if (lane == 63) wtot[wv] = run;
        __syncthreads();
        int wexcl = 0;
        for (int i = 0; i < wv; ++i) wexcl += wtot[i];
        int excl = wexcl + run - ls;
        #pragma unroll
        for (int i = 0; i < 2; ++i) {
            int idx = base + i;
            if (idx < NB) {
                int gb = bstart[idx] + off_g[(size_t)(4 * c) * NB + idx];
                h[idx]     = excl;
                delta[idx] = gb - excl;
                excl += v[i];
            }
        }
    }
    __syncthreads();

    // token = le(14) | dl(6)<<14 | b(11)<<20
    nit = 0;
    for (int k = t; k < CH_S; k += BS1, ++nit) {
        int d = dstv[nit];
        int b = d >> 6;
        int pos = atomicAdd(&h[b], 1);
        stage[pos] = (uint32_t)k | ((uint32_t)(d & 63) << 14) | ((uint32_t)b << 20);
    }
    __syncthreads();

    for (int i = t; i < CH_S; i += BS1) {
        uint32_t sv = stage[i];
        int le = sv & 0x3FFF;
        int dl = (sv >> 14) & 0x3F;
        int b  = sv >> 20;
        int e  = k0 + le;
        uint2 r;
        r.x = (uint32_t)src[e] | ((uint32_t)dl << 17);
        r.y = __float_as_uint(w[e]);
        rec1[delta[b] + i] = r;
    }
}

// ---------------------------------------------------------------------------
// Stage 4: scatter pass 2 — node-sort each bucket through an LDS stage.
// Emits 4 B rec2 = src(17) | w15(15)<<17.
// ---------------------------------------------------------------------------
__global__ void scatter2_kernel(const uint2* __restrict__ rec1,
                                const int* __restrict__ bstart, const int* __restrict__ tot,
                                uint32_t* __restrict__ rec2,
                                int* __restrict__ row_start, int* __restrict__ cnt) {
    __shared__ int h[BN];
    __shared__ int cur[BN];
    __shared__ uint32_t stage[S2_CAP];
    const int b  = blockIdx.x;
    const int s0 = bstart[b];
    const int n  = tot[b];
    if (threadIdx.x < BN) h[threadIdx.x] = 0;
    __syncthreads();
    for (int k = threadIdx.x; k < n; k += BLOCK)
        atomicAdd(&h[rec1[s0 + k].x >> 17], 1);
    __syncthreads();
    if (threadIdx.x < BN) {
        int v = h[threadIdx.x];
        int run = v;
        #pragma unroll
        for (int d = 1; d < 64; d <<= 1) {
            int u = __shfl_up(run, d);
            if (threadIdx.x >= d) run += u;
        }
        int excl = run - v;
        cur[threadIdx.x] = excl;
        int node = b * BN + threadIdx.x;
        if (node < N_NODES) { row_start[node] = s0 + excl; cnt[node] = v; }
    }
    __syncthreads();
    for (int k = threadIdx.x; k < n; k += BLOCK) {
        uint2 r = rec1[s0 + k];
        int dl = (int)(r.x >> 17);
        float wv = __uint_as_float(r.y);
        uint32_t w15 = (uint32_t)__float2uint_rn(wv * W_SCALE);
        uint32_t r2 = (r.x & 0x1FFFF) | (w15 << 17);
        int pos = atomicAdd(&cur[dl], 1);
        if (pos < S2_CAP) stage[pos] = r2;
        else              rec2[s0 + pos] = r2;
    }
    __syncthreads();
    for (int i = threadIdx.x; i < n && i < S2_CAP; i += BLOCK)
        rec2[s0 + i] = stage[i];
}

// ---------------------------------------------------------------------------
// Software grid barrier (sense-reversal, agent-scope atomics). Safe because
// PGRID=512 with __launch_bounds__(256,2) guarantees 2 blocks/CU co-residency
// (512 <= 256 CUs * 2). bar[0]=count, bar[1]=sense, zeroed by hipMemsetAsync.
// ---------------------------------------------------------------------------
__device__ __forceinline__ void grid_barrier(int* bar, int* local_sense) {
    __threadfence();                       // flush this thread's writes (agent)
    __syncthreads();
    if (threadIdx.x == 0) {
        int want = *local_sense ^ 1;
        *local_sense = want;
        int arrived = __hip_atomic_fetch_add(&bar[0], 1, __ATOMIC_ACQ_REL,
                                             __HIP_MEMORY_SCOPE_AGENT);
        if (arrived == PGRID - 1) {
            __hip_atomic_store(&bar[0], 0, __ATOMIC_RELAXED, __HIP_MEMORY_SCOPE_AGENT);
            __hip_atomic_store(&bar[1], want, __ATOMIC_RELEASE, __HIP_MEMORY_SCOPE_AGENT);
        } else {
            while (__hip_atomic_load(&bar[1], __ATOMIC_ACQUIRE,
                                     __HIP_MEMORY_SCOPE_AGENT) != want) {}
        }
    }
    __syncthreads();
    __threadfence();                       // invalidate stale cached lines
}

// ---------------------------------------------------------------------------
// Persistent layers kernel: all 5 layers, software grid barrier between them.
// Grid-stride over 800k lanes (8 lanes/node). Weights staged in LDS per layer.
// ---------------------------------------------------------------------------
struct LayerArgs {
    const __half* xpad;
    const uint32_t* rec;
    const int* row_start;
    const int* cnt;
    const float* wrel[5];
    const float* brel[5];
    const float* wroot[5];
    __half* pA; __half* pB;
    float*  oA; float*  oB;
    float*  out;
    int*    bar;
};

template<int DOUT, int SPH, int NDOUT, int NSPH, bool LAST>
__device__ __forceinline__ void gather_body(
        const __half* __restrict__ p, const float* __restrict__ oinit,
        const uint32_t* __restrict__ rec,
        const int* __restrict__ row_start, const int* __restrict__ cnt,
        const float* s_wrel, const float* s_wroot, const float* s_b,
        __half* __restrict__ pn, float* __restrict__ oinitn,
        float* __restrict__ out, int gtid, int NT) {
    for (int t = gtid; t < 8 * N_NODES; t += NT) {
        int node = t >> 3;
        int q    = t & 7;

        float af[SPH];
        #pragma unroll
        for (int i = 0; i < SPH; ++i) af[i] = 0.f;

        const int s = row_start[node];
        const int e = s + cnt[node];
        constexpr int NR = (SPH >= 8) ? SPH / 8 : 1;
        for (int k = s + q; k < e; k += 32) {
            uint32_t rv[4];
            float    wv[4];
            #pragma unroll
            for (int u = 0; u < 4; ++u) {
                int kk = k + 8 * u;
                int kc = kk < e ? kk : (e - 1);
                rv[u] = rec[kc];
                wv[u] = kk < e ? (float)(rv[u] >> 17) * W_INV : 0.f;
            }
            if constexpr (SPH >= 8) {
                uint4 raw[4 * NR];
                #pragma unroll
                for (int u = 0; u < 4; ++u) {
                    const uint4* ps = (const uint4*)(p + (size_t)(rv[u] & 0x1FFFF) * SPH);
                    #pragma unroll
                    for (int v = 0; v < NR; ++v) raw[u * NR + v] = ps[v];
                }
                #pragma unroll
                for (int u = 0; u < 4; ++u) {
                    float w = wv[u];
                    #pragma unroll
                    for (int v = 0; v < NR; ++v) {
                        const __half2* h = (const __half2*)&raw[u * NR + v];
                        #pragma unroll
                        for (int jj = 0; jj < 4; ++jj) {
                            af[v * 8 + 2 * jj]     += w * __low2float(h[jj]);
                            af[v * 8 + 2 * jj + 1] += w * __high2float(h[jj]);
                        }
                    }
                }
            } else {
                uint32_t raw[4];
                #pragma unroll
                for (int u = 0; u < 4; ++u)
                    raw[u] = *(const uint32_t*)(p + (size_t)(rv[u] & 0x1FFFF) * SPH);
                #pragma unroll
                for (int u = 0; u < 4; ++u) {
                    __half2 h = *(const __half2*)&raw[u];
                    af[0] += wv[u] * __low2float(h);
                    af[1] += wv[u] * __high2float(h);
                }
            }
        }
        #pragma unroll
        for (int i = 0; i < SPH; ++i) {
            af[i] += __shfl_xor(af[i], 1);
            af[i] += __shfl_xor(af[i], 2);
            af[i] += __shfl_xor(af[i], 4);
        }

        if constexpr (LAST) {
            if (q == 0) {
                float o0 = af[0] + oinit[(size_t)node * 2 + 0];
                float o1 = af[1] + oinit[(size_t)node * 2 + 1];
                float m = fmaxf(o0, o1);
                float e0 = __expf(o0 - m), e1 = __expf(o1 - m);
                float inv = 1.f / (e0 + e1);
                out[(size_t)node * 2 + 0] = e0 * inv;
                out[(size_t)node * 2 + 1] = e1 * inv;
            }
        } else {
            float ov[DOUT];
            #pragma unroll
            for (int j = 0; j < DOUT; ++j)
                ov[j] = fmaxf(af[j] + oinit[(size_t)node * DOUT + j], 0.f);

            if (q < NSPH / 2) {
                float pk[2] = {0.f, 0.f};
                #pragma unroll
                for (int kk = 0; kk < 2; ++kk) {
                    int k = 2 * q + kk;
                    if (k < NDOUT) {
                        float sacc = 0.f;
                        #pragma unroll
                        for (int j = 0; j < DOUT; ++j) sacc += ov[j] * s_wrel[j * NDOUT + k];
                        pk[kk] = sacc;
                    }
                }
                ((__half2*)(pn + (size_t)node * NSPH))[q] =
                    __halves2half2(__float2half(pk[0]), __float2half(pk[1]));
            }
            #pragma unroll
            for (int kk = 0; kk < 2; ++kk) {
                int k = q + kk * 8;
                if (k < NDOUT) {
                    float sacc = s_b[k];
                    #pragma unroll
                    for (int j = 0; j < DOUT; ++j) sacc += ov[j] * s_wroot[j * NDOUT + k];
                    oinitn[(size_t)node * NDOUT + k] = sacc;
                }
            }
        }
    }
}

__global__ void __launch_bounds__(BLOCK, 2)
layers_kernel(LayerArgs a) {
    __shared__ float s_wrel0[6 * 20], s_wroot0[6 * 20], s_b0[20];
    __shared__ float s_wrel[20 * 15], s_wroot[20 * 15], s_b[16];

    const int gtid = blockIdx.x * blockDim.x + threadIdx.x;
    const int NT   = gridDim.x * blockDim.x;
    int sense = 0;

    // ---- stage L0 weights (own + L1 emit transform) ----
    for (int t = threadIdx.x; t < 120; t += BLOCK) {
        s_wrel0[t]  = a.wrel[0][t];
        s_wroot0[t] = a.wroot[0][t];
    }
    for (int t = threadIdx.x; t < 300; t += BLOCK) {
        s_wrel[t]  = a.wrel[1][t];
        s_wroot[t] = a.wroot[1][t];
    }
    if (threadIdx.x < 20) s_b0[threadIdx.x] = a.brel[0][threadIdx.x];
    if (threadIdx.x < 15) s_b[threadIdx.x]  = a.brel[1][threadIdx.x];
    __syncthreads();

    // ---- layer 0: aggregate xpad, relu, emit p1 + oinit1 ----
    for (int t = gtid; t < 8 * N_NODES; t += NT) {
        int node = t >> 3;
        int q    = t & 7;
        float agg[6] = {0.f, 0.f, 0.f, 0.f, 0.f, 0.f};
        const int s = a.row_start[node];
        const int e = s + a.cnt[node];
        for (int k = s + q; k < e; k += 32) {
            uint32_t rv[4];
            float    wv[4];
            #pragma unroll
            for (int u = 0; u < 4; ++u) {
                int kk = k + 8 * u;
                int kc = kk < e ? kk : (e - 1);
                rv[u] = a.rec[kc];
                wv[u] = kk < e ? (float)(rv[u] >> 17) * W_INV : 0.f;
            }
            uint4 raw[4];
            #pragma unroll
            for (int u = 0; u < 4; ++u)
                raw[u] = *(const uint4*)(a.xpad + (size_t)(rv[u] & 0x1FFFF) * 8);
            #pragma unroll
            for (int u = 0; u < 4; ++u) {
                const __half2* h = (const __half2*)&raw[u];
                float w = wv[u];
                agg[0] += w * __low2float(h[0]);  agg[1] += w * __high2float(h[0]);
                agg[2] += w * __low2float(h[1]);  agg[3] += w * __high2float(h[1]);
                agg[4] += w * __low2float(h[2]);  agg[5] += w * __high2float(h[2]);
            }
        }
        #pragma unroll
        for (int i = 0; i < 6; ++i) {
            agg[i] += __shfl_xor(agg[i], 1);
            agg[i] += __shfl_xor(agg[i], 2);
            agg[i] += __shfl_xor(agg[i], 4);
        }
        uint4 raws = *(const uint4*)(a.xpad + (size_t)node * 8);
        const __half2* hs = (const __half2*)&raws;
        float xv[6] = { __low2float(hs[0]), __high2float(hs[0]),
                        __low2float(hs[1]), __high2float(hs[1]),
                        __low2float(hs[2]), __high2float(hs[2]) };
        float ov[20];
        #pragma unroll
        for (int j = 0; j < 20; ++j) {
            float o = s_b0[j];
            #pragma unroll
            for (int i = 0; i < 6; ++i)
                o += agg[i] * s_wrel0[i * 20 + j] + xv[i] * s_wroot0[i * 20 + j];
            ov[j] = fmaxf(o, 0.f);
        }
        {
            float pk[2] = {0.f, 0.f};
            #pragma unroll
            for (int kk = 0; kk < 2; ++kk) {
                int k = 2 * q + kk;
                if (k < 15) {
                    float sacc = 0.f;
                    #pragma unroll
                    for (int j = 0; j < 20; ++j) sacc += ov[j] * s_wrel[j * 15 + k];
                    pk[kk] = sacc;
                }
            }
            ((__half2*)(a.pA + (size_t)node * 16))[q] =
                __halves2half2(__float2half(pk[0]), __float2half(pk[1]));
        }
        #pragma unroll
        for (int kk = 0; kk < 2; ++kk) {
            int k = q + kk * 8;
            if (k < 15) {
                float sacc = s_b[k];
                #pragma unroll
                for (int j = 0; j < 20; ++j) sacc += ov[j] * s_wroot[j * 15 + k];
                a.oA[(size_t)node * 15 + k] = sacc;
            }
        }
    }
    grid_barrier(a.bar, &sense);

    // ---- g1: agg p1 [15,16] -> p2 [10,16] + oinit2 ----
    for (int t = threadIdx.x; t < 150; t += BLOCK) {
        s_wrel[t]  = a.wrel[2][t];
        s_wroot[t] = a.wroot[2][t];
    }
    if (threadIdx.x < 10) s_b[threadIdx.x] = a.brel[2][threadIdx.x];
    __syncthreads();
    gather_body<15, 16, 10, 16, false>(a.pA, a.oA, a.rec, a.row_start, a.cnt,
                                       s_wrel, s_wroot, s_b, a.pB, a.oB, nullptr, gtid, NT);
    grid_barrier(a.bar, &sense);

    // ---- g2: agg p2 [10,16] -> p3 [5,8] + oinit3 ----
    for (int t = threadIdx.x; t < 50; t += BLOCK) {
        s_wrel[t]  = a.wrel[3][t];
        s_wroot[t] = a.wroot[3][t];
    }
    if (threadIdx.x < 5) s_b[threadIdx.x] = a.brel[3][threadIdx.x];
    __syncthreads();
    gather_body<10, 16, 5, 8, false>(a.pB, a.oB, a.rec, a.row_start, a.cnt,
                                     s_wrel, s_wroot, s_b, a.pA, a.oA, nullptr, gtid, NT);
    grid_barrier(a.bar, &sense);

    // ---- g3: agg p3 [5,8] -> p4 [2,2] + oinit4 ----
    for (int t = threadIdx.x; t < 10; t += BLOCK) {
        s_wrel[t]  = a.wrel[4][t];
        s_wroot[t] = a.wroot[4][t];
    }
    if (threadIdx.x < 2) s_b[threadIdx.x] = a.brel[4][threadIdx.x];
    __syncthreads();
    gather_body<5, 8, 2, 2, false>(a.pA, a.oA, a.rec, a.row_start, a.cnt,
                                   s_wrel, s_wroot, s_b, a.pB, a.oB, nullptr, gtid, NT);
    grid_barrier(a.bar, &sense);

    // ---- g4: agg p4 [2,2], softmax -> out ----
    gather_body<2, 2, 0, 0, true>(a.pB, a.oB, a.rec, a.row_start, a.cnt,
                                  nullptr, nullptr, nullptr,
                                  nullptr, nullptr, a.out, gtid, NT);
}

// ---------------------------------------------------------------------------

extern "C" void kernel_launch(void* const* d_in, const int* in_sizes, int n_in,
                              void* d_out, int out_size, void* d_ws, size_t ws_size,
                              hipStream_t stream) {
    const float* x  = (const float*)d_in[0];
    const int*   ei = (const int*)d_in[1];
    const float* ew = (const float*)d_in[2];

    char* ws = (char*)d_ws;
    size_t off = 0;
    auto alloc = [&](size_t bytes) -> void* {
        void* ptr = ws + off;
        off += (bytes + 255) & ~(size_t)255;
        return ptr;
    };
    // regionA: rec1 during sort (25.6 MB); p/oinit ping-pong during layers
    char*     regionA   = (char*)alloc((size_t)N_EDGES * 8);
    uint2*    rec1      = (uint2*)regionA;
    __half*   pA        = (__half*)regionA;                              // 3.2 MB
    __half*   pB        = (__half*)(regionA + (size_t)4  * 1024 * 1024); // 3.2 MB
    float*    oA        = (float*)(regionA + (size_t)8  * 1024 * 1024);  // 6 MB
    float*    oB        = (float*)(regionA + (size_t)16 * 1024 * 1024);  // 6 MB
    uint32_t* rec2      = (uint32_t*)alloc((size_t)N_EDGES * 4);         // 12.8 MB
    __half*   xpad      = (__half*)alloc((size_t)N_NODES * 8 * 2);       // 1.6 MB
    int*      hist_g    = (int*)alloc((size_t)NCH_H * NB * 4);           // 6.4 MB
    int*      off_g     = (int*)alloc((size_t)NCH_H * NB * 4);           // 6.4 MB
    int*      tot       = (int*)alloc((size_t)NB * 4);
    int*      bstart    = (int*)alloc((size_t)NB * 4);
    int*      row_start = (int*)alloc((size_t)N_NODES * 4);
    int*      cntb      = (int*)alloc((size_t)N_NODES * 4);
    int*      bar       = (int*)alloc(256);                              // barrier words

    const int* srcv = ei;            // edge_index row 0
    const int* dstv = ei + N_EDGES;  // edge_index row 1

    hipMemsetAsync(bar, 0, 8, stream);   // count=0, sense=0 (ws is poisoned)

    hist_kernel     <<<NCH_H, BLOCK, 0, stream>>>(dstv, hist_g, x, xpad);
    chunkscan_kernel<<<(NB + 3) / 4, BLOCK, 0, stream>>>(hist_g, off_g, tot);
    scan_kernel     <<<1, SCAN_T, 0, stream>>>(tot, bstart);
    scatter1_kernel <<<NCH_S, BS1, 0, stream>>>(srcv, dstv, ew, bstart, off_g, rec1);
    scatter2_kernel <<<NB, BLOCK, 0, stream>>>(rec1, bstart, tot, rec2, row_start, cntb);

    LayerArgs la;
    la.xpad = xpad; la.rec = rec2; la.row_start = row_start; la.cnt = cntb;
    for (int i = 0; i < 5; ++i) {
        la.wrel[i]  = (const float*)d_in[3 + 3 * i];
        la.brel[i]  = (const float*)d_in[4 + 3 * i];
        la.wroot[i] = (const float*)d_in[5 + 3 * i];
    }
    la.pA = pA; la.pB = pB; la.oA = oA; la.oB = oB; la.out = (float*)d_out;
    la.bar = bar;

    layers_kernel<<<PGRID, BLOCK, 0, stream>>>(la);
}

// Round 12
// 330.990 us; speedup vs baseline: 3.0141x; 3.0141x over previous
//
#include <hip/hip_runtime.h>
#include <hip/hip_fp16.h>
#include <stdint.h>

#define N_NODES 100000
#define N_EDGES 3200000
#define BN      64                    // nodes per dst-bucket
#define NB      1563                  // ceil(N_NODES / BN)
// histogram granularity (fine)
#define NCH_H   1024
#define CH_H    (N_EDGES / NCH_H)     // 3125
#define CPL     (NCH_H / 64)          // 16 chunks per lane in chunkscan
#define PAD_PER 98                    // nodes padded per hist block
// scatter granularity (coarse, for long coalesced runs)
#define NCH_S   256
#define CH_S    (N_EDGES / NCH_S)     // 12500
#define BS1     1024                  // scatter1 block size
#define S1_IT   ((CH_S + BS1 - 1) / BS1)
#define S2_CAP  2560                  // scatter2 LDS stage capacity
#define BLOCK   256
#define LPN     16                    // lanes per node in layer kernels
#define W_SCALE 32767.0f
#define W_INV   (1.0f / 32767.0f)

// ---------------------------------------------------------------------------
// Stage 1: per-subchunk bucket histogram + fused x->fp16 padding
// ---------------------------------------------------------------------------
__global__ void hist_kernel(const int* __restrict__ dst, int* __restrict__ hist_g,
                            const float* __restrict__ x, __half* __restrict__ xpad) {
    __shared__ int h[NB];
    for (int b = threadIdx.x; b < NB; b += BLOCK) h[b] = 0;
    {
        int i = blockIdx.x * PAD_PER + threadIdx.x;
        if (threadIdx.x < PAD_PER && i < N_NODES) {
            const float* xr = x + (size_t)i * 6;
            __half2 hh[4];
            hh[0] = __halves2half2(__float2half(xr[0]), __float2half(xr[1]));
            hh[1] = __halves2half2(__float2half(xr[2]), __float2half(xr[3]));
            hh[2] = __halves2half2(__float2half(xr[4]), __float2half(xr[5]));
            hh[3] = __halves2half2(__float2half(0.f),   __float2half(0.f));
            *(uint4*)(xpad + (size_t)i * 8) = *(uint4*)hh;
        }
    }
    __syncthreads();
    const int c  = blockIdx.x;
    const int k0 = c * CH_H;
    for (int k = threadIdx.x; k < CH_H; k += BLOCK)
        atomicAdd(&h[dst[k0 + k] >> 6], 1);
    __syncthreads();
    for (int b = threadIdx.x; b < NB; b += BLOCK)
        hist_g[c * NB + b] = h[b];
}

// ---------------------------------------------------------------------------
// Stage 2a: per-bucket exclusive scan over the 1024 subchunk counts
// ---------------------------------------------------------------------------
__global__ void chunkscan_kernel(const int* __restrict__ hist_g,
                                 int* __restrict__ off_g, int* __restrict__ tot) {
    int w    = (blockIdx.x * blockDim.x + threadIdx.x) >> 6;
    int lane = threadIdx.x & 63;
    if (w >= NB) return;
    int v[CPL];
    int ls = 0;
    const int cbase = lane * CPL;
    #pragma unroll
    for (int i = 0; i < CPL; ++i) { v[i] = hist_g[(cbase + i) * NB + w]; ls += v[i]; }
    int run = ls;
    #pragma unroll
    for (int d = 1; d < 64; d <<= 1) {
        int u = __shfl_up(run, d);
        if (lane >= d) run += u;
    }
    int acc = run - ls;
    #pragma unroll
    for (int i = 0; i < CPL; ++i) { off_g[(cbase + i) * NB + w] = acc; acc += v[i]; }
    if (lane == 63) tot[w] = acc;
}

// ---------------------------------------------------------------------------
// Stage 2b: exclusive scan of 1563 bucket totals (one wg)
// ---------------------------------------------------------------------------
#define SCAN_T   1024
#define SCAN_PER 2
__global__ void scan_kernel(const int* __restrict__ cnt, int* __restrict__ bstart) {
    __shared__ int part[SCAN_T];
    int t = threadIdx.x;
    int local[SCAN_PER];
    int s = 0;
    #pragma unroll
    for (int i = 0; i < SCAN_PER; ++i) {
        int idx = t * SCAN_PER + i;
        int v = (idx < NB) ? cnt[idx] : 0;
        local[i] = s;
        s += v;
    }
    part[t] = s;
    __syncthreads();
    for (int off = 1; off < SCAN_T; off <<= 1) {
        int v = (t >= off) ? part[t - off] : 0;
        __syncthreads();
        part[t] += v;
        __syncthreads();
    }
    int excl = part[t] - s;
    #pragma unroll
    for (int i = 0; i < SCAN_PER; ++i) {
        int idx = t * SCAN_PER + i;
        if (idx < NB) bstart[idx] = excl + local[i];
    }
}

// ---------------------------------------------------------------------------
// Stage 3: scatter pass 1, stage-and-flush (8 B records, proven R7/R9 config).
// rec1: x = src(17) | dl(6)<<17 ; y = weight fp32 bits.
// ---------------------------------------------------------------------------
__global__ void __launch_bounds__(BS1)
scatter1_kernel(const int* __restrict__ src, const int* __restrict__ dst,
                const float* __restrict__ w,
                const int* __restrict__ bstart, const int* __restrict__ off_g,
                uint2* __restrict__ rec1) {
    __shared__ uint32_t stage[CH_S];   // 50000 B
    __shared__ int h[NB];
    __shared__ int delta[NB];
    __shared__ int wtot[BS1 / 64];

    const int c  = blockIdx.x;
    const int k0 = c * CH_S;
    const int t  = threadIdx.x;

    for (int b = t; b < NB; b += BS1) h[b] = 0;
    __syncthreads();
    int dstv[S1_IT];
    int nit = 0;
    for (int k = t; k < CH_S; k += BS1, ++nit) {
        int d = dst[k0 + k];
        dstv[nit] = d;
        atomicAdd(&h[d >> 6], 1);
    }
    __syncthreads();

    {
        const int base = t * 2;          // 2048 >= NB
        int v[2], ls = 0;
        #pragma unroll
        for (int i = 0; i < 2; ++i) {
            int idx = base + i;
            v[i] = (idx < NB) ? h[idx] : 0;
            ls += v[i];
        }
        int lane = t & 63, wv = t >> 6;
        int run = ls;
        #pragma unroll
        for (int d = 1; d < 64; d <<= 1) {
            int u = __shfl_up(run, d);
            if (lane >= d) run += u;
        }
        if (lane == 63) wtot[wv] = run;
        __syncthreads();
        int wexcl = 0;
        for (int i = 0; i < wv; ++i) wexcl += wtot[i];
        int excl = wexcl + run - ls;
        #pragma unroll
        for (int i = 0; i < 2; ++i) {
            int idx = base + i;
            if (idx < NB) {
                int gb = bstart[idx] + off_g[(size_t)(4 * c) * NB + idx];
                h[idx]     = excl;
                delta[idx] = gb - excl;
                excl += v[i];
            }
        }
    }
    __syncthreads();

    // token = le(14) | dl(6)<<14 | b(11)<<20
    nit = 0;
    for (int k = t; k < CH_S; k += BS1, ++nit) {
        int d = dstv[nit];
        int b = d >> 6;
        int pos = atomicAdd(&h[b], 1);
        stage[pos] = (uint32_t)k | ((uint32_t)(d & 63) << 14) | ((uint32_t)b << 20);
    }
    __syncthreads();

    for (int i = t; i < CH_S; i += BS1) {
        uint32_t sv = stage[i];
        int le = sv & 0x3FFF;
        int dl = (sv >> 14) & 0x3F;
        int b  = sv >> 20;
        int e  = k0 + le;
        uint2 r;
        r.x = (uint32_t)src[e] | ((uint32_t)dl << 17);
        r.y = __float_as_uint(w[e]);
        rec1[delta[b] + i] = r;
    }
}

// ---------------------------------------------------------------------------
// Stage 4: scatter pass 2 — node-sort each bucket. rec1 is read from HBM
// exactly ONCE (cached in LDS); sort + flush happen from/to LDS.
// Emits 4 B rec2 = src(17) | w15(15)<<17.
// ---------------------------------------------------------------------------
__global__ void scatter2_kernel(const uint2* __restrict__ rec1,
                                const int* __restrict__ bstart, const int* __restrict__ tot,
                                uint32_t* __restrict__ rec2,
                                int* __restrict__ row_start, int* __restrict__ cnt) {
    __shared__ int h[BN];
    __shared__ int cur[BN];
    __shared__ uint2 sin[S2_CAP];        // 20.5 KB: raw records, read-once cache
    __shared__ uint32_t sout[S2_CAP];    // 10.2 KB: sorted output stage
    const int b  = blockIdx.x;
    const int s0 = bstart[b];
    const int n  = tot[b];
    if (threadIdx.x < BN) h[threadIdx.x] = 0;
    __syncthreads();
    for (int k = threadIdx.x; k < n; k += BLOCK) {
        uint2 r = rec1[s0 + k];
        if (k < S2_CAP) sin[k] = r;
        atomicAdd(&h[r.x >> 17], 1);
    }
    __syncthreads();
    if (threadIdx.x < BN) {
        int v = h[threadIdx.x];
        int run = v;
        #pragma unroll
        for (int d = 1; d < 64; d <<= 1) {
            int u = __shfl_up(run, d);
            if (threadIdx.x >= d) run += u;
        }
        int excl = run - v;
        cur[threadIdx.x] = excl;
        int node = b * BN + threadIdx.x;
        if (node < N_NODES) { row_start[node] = s0 + excl; cnt[node] = v; }
    }
    __syncthreads();
    for (int k = threadIdx.x; k < n; k += BLOCK) {
        uint2 r = (k < S2_CAP) ? sin[k] : rec1[s0 + k];
        int dl = (int)(r.x >> 17);
        float wv = __uint_as_float(r.y);
        uint32_t w15 = (uint32_t)__float2uint_rn(wv * W_SCALE);
        uint32_t r2 = (r.x & 0x1FFFF) | (w15 << 17);
        int pos = atomicAdd(&cur[dl], 1);
        if (pos < S2_CAP) sout[pos] = r2;
        else              rec2[s0 + pos] = r2;
    }
    __syncthreads();
    for (int i = threadIdx.x; i < n && i < S2_CAP; i += BLOCK)
        rec2[s0 + i] = sout[i];
}

// ---------------------------------------------------------------------------
// Layer 0 fused (16 lanes/node): aggregate xpad (6, fp16) batched, relu,
// emit p1 (fp16) + oinit1.
// ---------------------------------------------------------------------------
__global__ void layer0_kernel(const __half* __restrict__ xpad,
                              const uint32_t* __restrict__ rec,
                              const int* __restrict__ row_start, const int* __restrict__ cnt,
                              const float* __restrict__ wrel0, const float* __restrict__ brel0,
                              const float* __restrict__ wroot0,
                              const float* __restrict__ wrel1, const float* __restrict__ brel1,
                              const float* __restrict__ wroot1,
                              __half* __restrict__ pn, float* __restrict__ oinitn) {
    __shared__ float s_wrel0[6 * 20], s_wroot0[6 * 20], s_b0[20];
    __shared__ float s_wrel1[20 * 15], s_wroot1[20 * 15], s_b1[15];
    for (int t = threadIdx.x; t < 120; t += BLOCK) {
        s_wrel0[t]  = wrel0[t];
        s_wroot0[t] = wroot0[t];
    }
    for (int t = threadIdx.x; t < 300; t += BLOCK) {
        s_wrel1[t]  = wrel1[t];
        s_wroot1[t] = wroot1[t];
    }
    if (threadIdx.x < 20) s_b0[threadIdx.x] = brel0[threadIdx.x];
    if (threadIdx.x < 15) s_b1[threadIdx.x] = brel1[threadIdx.x];
    __syncthreads();

    int t = blockIdx.x * blockDim.x + threadIdx.x;
    int node = t >> 4;
    int q    = t & 15;

    float agg[6] = {0.f, 0.f, 0.f, 0.f, 0.f, 0.f};
    const int s = row_start[node];
    const int e = s + cnt[node];
    for (int k = s + q; k < e; k += 2 * LPN) {
        uint32_t rv[2];
        float    wv[2];
        #pragma unroll
        for (int u = 0; u < 2; ++u) {
            int kk = k + LPN * u;
            int kc = kk < e ? kk : (e - 1);
            rv[u] = rec[kc];
            wv[u] = kk < e ? (float)(rv[u] >> 17) * W_INV : 0.f;
        }
        uint4 raw[2];
        #pragma unroll
        for (int u = 0; u < 2; ++u)
            raw[u] = *(const uint4*)(xpad + (size_t)(rv[u] & 0x1FFFF) * 8);
        #pragma unroll
        for (int u = 0; u < 2; ++u) {
            const __half2* h = (const __half2*)&raw[u];
            float w = wv[u];
            agg[0] += w * __low2float(h[0]);  agg[1] += w * __high2float(h[0]);
            agg[2] += w * __low2float(h[1]);  agg[3] += w * __high2float(h[1]);
            agg[4] += w * __low2float(h[2]);  agg[5] += w * __high2float(h[2]);
        }
    }
    #pragma unroll
    for (int i = 0; i < 6; ++i) {
        agg[i] += __shfl_xor(agg[i], 1);
        agg[i] += __shfl_xor(agg[i], 2);
        agg[i] += __shfl_xor(agg[i], 4);
        agg[i] += __shfl_xor(agg[i], 8);
    }
    uint4 raws = *(const uint4*)(xpad + (size_t)node * 8);
    const __half2* hs = (const __half2*)&raws;
    float xv[6] = { __low2float(hs[0]), __high2float(hs[0]),
                    __low2float(hs[1]), __high2float(hs[1]),
                    __low2float(hs[2]), __high2float(hs[2]) };
    float ov[20];
    #pragma unroll
    for (int j = 0; j < 20; ++j) {
        float o = s_b0[j];
        #pragma unroll
        for (int i = 0; i < 6; ++i)
            o += agg[i] * s_wrel0[i * 20 + j] + xv[i] * s_wroot0[i * 20 + j];
        ov[j] = fmaxf(o, 0.f);
    }
    if (q < 8) {   // p1 slot q of 8 (NSPH=16)
        float pk[2] = {0.f, 0.f};
        #pragma unroll
        for (int kk = 0; kk < 2; ++kk) {
            int k = 2 * q + kk;
            if (k < 15) {
                float sacc = 0.f;
                #pragma unroll
                for (int j = 0; j < 20; ++j) sacc += ov[j] * s_wrel1[j * 15 + k];
                pk[kk] = sacc;
            }
        }
        ((__half2*)(pn + (size_t)node * 16))[q] =
            __halves2half2(__float2half(pk[0]), __float2half(pk[1]));
    }
    if (q < 15) {  // oinit1 element q
        float sacc = s_b1[q];
        #pragma unroll
        for (int j = 0; j < 20; ++j) sacc += ov[j] * s_wroot1[j * 15 + q];
        oinitn[(size_t)node * 15 + q] = sacc;
    }
}

// ---------------------------------------------------------------------------
// Fused gather layer (16 lanes/node): batched aggregate p_i, relu + oinit_i,
// emit p_{i+1} + oinit_{i+1}. LAST: softmax.
// ---------------------------------------------------------------------------
template<int DOUT, int SPH, int NDOUT, int NSPH, bool LAST>
__global__ void gather_kernel(const __half* __restrict__ p, const float* __restrict__ oinit,
                              const uint32_t* __restrict__ rec,
                              const int* __restrict__ row_start, const int* __restrict__ cnt,
                              const float* __restrict__ wrel_n, const float* __restrict__ brel_n,
                              const float* __restrict__ wroot_n,
                              __half* __restrict__ pn, float* __restrict__ oinitn,
                              float* __restrict__ out) {
    __shared__ float s_wrel[LAST ? 1 : DOUT * NDOUT];
    __shared__ float s_wroot[LAST ? 1 : DOUT * NDOUT];
    __shared__ float s_b[LAST ? 1 : (NDOUT > 0 ? NDOUT : 1)];
    if constexpr (!LAST) {
        for (int t = threadIdx.x; t < DOUT * NDOUT; t += BLOCK) {
            s_wrel[t]  = wrel_n[t];
            s_wroot[t] = wroot_n[t];
        }
        if (threadIdx.x < NDOUT) s_b[threadIdx.x] = brel_n[threadIdx.x];
        __syncthreads();
    }

    int t = blockIdx.x * blockDim.x + threadIdx.x;
    int node = t >> 4;
    int q    = t & 15;

    float af[SPH];
    #pragma unroll
    for (int i = 0; i < SPH; ++i) af[i] = 0.f;

    const int s = row_start[node];
    const int e = s + cnt[node];
    constexpr int NR = (SPH >= 8) ? SPH / 8 : 1;
    for (int k = s + q; k < e; k += 2 * LPN) {
        uint32_t rv[2];
        float    wv[2];
        #pragma unroll
        for (int u = 0; u < 2; ++u) {
            int kk = k + LPN * u;
            int kc = kk < e ? kk : (e - 1);
            rv[u] = rec[kc];
            wv[u] = kk < e ? (float)(rv[u] >> 17) * W_INV : 0.f;
        }
        if constexpr (SPH >= 8) {
            uint4 raw[2 * NR];
            #pragma unroll
            for (int u = 0; u < 2; ++u) {
                const uint4* ps = (const uint4*)(p + (size_t)(rv[u] & 0x1FFFF) * SPH);
                #pragma unroll
                for (int v = 0; v < NR; ++v) raw[u * NR + v] = ps[v];
            }
            #pragma unroll
            for (int u = 0; u < 2; ++u) {
                float w = wv[u];
                #pragma unroll
                for (int v = 0; v < NR; ++v) {
                    const __half2* h = (const __half2*)&raw[u * NR + v];
                    #pragma unroll
                    for (int jj = 0; jj < 4; ++jj) {
                        af[v * 8 + 2 * jj]     += w * __low2float(h[jj]);
                        af[v * 8 + 2 * jj + 1] += w * __high2float(h[jj]);
                    }
                }
            }
        } else {
            uint32_t raw[2];
            #pragma unroll
            for (int u = 0; u < 2; ++u)
                raw[u] = *(const uint32_t*)(p + (size_t)(rv[u] & 0x1FFFF) * SPH);
            #pragma unroll
            for (int u = 0; u < 2; ++u) {
                __half2 h = *(const __half2*)&raw[u];
                af[0] += wv[u] * __low2float(h);
                af[1] += wv[u] * __high2float(h);
            }
        }
    }
    #pragma unroll
    for (int i = 0; i < SPH; ++i) {
        af[i] += __shfl_xor(af[i], 1);
        af[i] += __shfl_xor(af[i], 2);
        af[i] += __shfl_xor(af[i], 4);
        af[i] += __shfl_xor(af[i], 8);
    }

    if constexpr (LAST) {
        if (q == 0) {
            float o0 = af[0] + oinit[(size_t)node * 2 + 0];
            float o1 = af[1] + oinit[(size_t)node * 2 + 1];
            float m = fmaxf(o0, o1);
            float e0 = __expf(o0 - m), e1 = __expf(o1 - m);
            float inv = 1.f / (e0 + e1);
            out[(size_t)node * 2 + 0] = e0 * inv;
            out[(size_t)node * 2 + 1] = e1 * inv;
        }
    } else {
        float ov[DOUT];
        #pragma unroll
        for (int j = 0; j < DOUT; ++j)
            ov[j] = fmaxf(af[j] + oinit[(size_t)node * DOUT + j], 0.f);

        if (q < NSPH / 2) {
            float pk[2] = {0.f, 0.f};
            #pragma unroll
            for (int kk = 0; kk < 2; ++kk) {
                int k = 2 * q + kk;
                if (k < NDOUT) {
                    float sacc = 0.f;
                    #pragma unroll
                    for (int j = 0; j < DOUT; ++j) sacc += ov[j] * s_wrel[j * NDOUT + k];
                    pk[kk] = sacc;
                }
            }
            ((__half2*)(pn + (size_t)node * NSPH))[q] =
                __halves2half2(__float2half(pk[0]), __float2half(pk[1]));
        }
        if (q < NDOUT) {
            float sacc = s_b[q];
            #pragma unroll
            for (int j = 0; j < DOUT; ++j) sacc += ov[j] * s_wroot[j * NDOUT + q];
            oinitn[(size_t)node * NDOUT + q] = sacc;
        }
    }
}

// ---------------------------------------------------------------------------

extern "C" void kernel_launch(void* const* d_in, const int* in_sizes, int n_in,
                              void* d_out, int out_size, void* d_ws, size_t ws_size,
                              hipStream_t stream) {
    const float* x  = (const float*)d_in[0];
    const int*   ei = (const int*)d_in[1];
    const float* ew = (const float*)d_in[2];
    const float* wrel[5]  = { (const float*)d_in[3], (const float*)d_in[6],
                              (const float*)d_in[9], (const float*)d_in[12],
                              (const float*)d_in[15] };
    const float* brel[5]  = { (const float*)d_in[4], (const float*)d_in[7],
                              (const float*)d_in[10], (const float*)d_in[13],
                              (const float*)d_in[16] };
    const float* wroot[5] = { (const float*)d_in[5], (const float*)d_in[8],
                              (const float*)d_in[11], (const float*)d_in[14],
                              (const float*)d_in[17] };

    char* ws = (char*)d_ws;
    size_t off = 0;
    auto alloc = [&](size_t bytes) -> void* {
        void* ptr = ws + off;
        off += (bytes + 255) & ~(size_t)255;
        return ptr;
    };
    // regionA: rec1 during sort (25.6 MB); p/oinit ping-pong during layers
    char*     regionA   = (char*)alloc((size_t)N_EDGES * 8);
    uint2*    rec1      = (uint2*)regionA;
    __half*   pA        = (__half*)regionA;                              // 3.2 MB
    __half*   pB        = (__half*)(regionA + (size_t)4  * 1024 * 1024); // 3.2 MB
    float*    oA        = (float*)(regionA + (size_t)8  * 1024 * 1024);  // 6 MB
    float*    oB        = (float*)(regionA + (size_t)16 * 1024 * 1024);  // 6 MB
    uint32_t* rec2      = (uint32_t*)alloc((size_t)N_EDGES * 4);         // 12.8 MB
    __half*   xpad      = (__half*)alloc((size_t)N_NODES * 8 * 2);       // 1.6 MB
    int*      hist_g    = (int*)alloc((size_t)NCH_H * NB * 4);           // 6.4 MB
    int*      off_g     = (int*)alloc((size_t)NCH_H * NB * 4);           // 6.4 MB
    int*      tot       = (int*)alloc((size_t)NB * 4);
    int*      bstart    = (int*)alloc((size_t)NB * 4);
    int*      row_start = (int*)alloc((size_t)N_NODES * 4);
    int*      cntb      = (int*)alloc((size_t)N_NODES * 4);

    const int* srcv = ei;            // edge_index row 0
    const int* dstv = ei + N_EDGES;  // edge_index row 1

    const int gN16 = (LPN * N_NODES + BLOCK - 1) / BLOCK;   // 6250

    hist_kernel     <<<NCH_H, BLOCK, 0, stream>>>(dstv, hist_g, x, xpad);
    chunkscan_kernel<<<(NB + 3) / 4, BLOCK, 0, stream>>>(hist_g, off_g, tot);
    scan_kernel     <<<1, SCAN_T, 0, stream>>>(tot, bstart);
    scatter1_kernel <<<NCH_S, BS1, 0, stream>>>(srcv, dstv, ew, bstart, off_g, rec1);
    scatter2_kernel <<<NB, BLOCK, 0, stream>>>(rec1, bstart, tot, rec2, row_start, cntb);

    // L0 fused: 6 -> 20 (relu) -> emit p1 [15, SPH 16] + oinit1
    layer0_kernel<<<gN16, BLOCK, 0, stream>>>(xpad, rec2, row_start, cntb,
                                              wrel[0], brel[0], wroot[0],
                                              wrel[1], brel[1], wroot[1], pA, oA);
    // g1: agg p1, out1 [15] -> p2 [10, SPH 16] + oinit2
    gather_kernel<15, 16, 10, 16, false><<<gN16, BLOCK, 0, stream>>>(
        pA, oA, rec2, row_start, cntb, wrel[2], brel[2], wroot[2], pB, oB, nullptr);
    // g2: agg p2, out2 [10] -> p3 [5, SPH 8] + oinit3
    gather_kernel<10, 16, 5, 8, false><<<gN16, BLOCK, 0, stream>>>(
        pB, oB, rec2, row_start, cntb, wrel[3], brel[3], wroot[3], pA, oA, nullptr);
    // g3: agg p3, out3 [5] -> p4 [2, SPH 2] + oinit4
    gather_kernel<5, 8, 2, 2, false><<<gN16, BLOCK, 0, stream>>>(
        pA, oA, rec2, row_start, cntb, wrel[4], brel[4], wroot[4], pB, oB, nullptr);
    // g4: agg p4, softmax -> d_out
    gather_kernel<2, 2, 0, 0, true><<<gN16, BLOCK, 0, stream>>>(
        pB, oB, rec2, row_start, cntb, nullptr, nullptr, nullptr,
        nullptr, nullptr, (float*)d_out);
}

// Round 13
// 328.513 us; speedup vs baseline: 3.0368x; 1.0075x over previous
//
#include <hip/hip_runtime.h>
#include <hip/hip_fp16.h>
#include <stdint.h>

#define N_NODES 100000
#define N_EDGES 3200000
#define BN      64                    // nodes per dst-bucket
#define NB      1563                  // ceil(N_NODES / BN)
// histogram granularity (fine)
#define NCH_H   1024
#define CH_H    (N_EDGES / NCH_H)     // 3125
#define CPL     (NCH_H / 64)          // 16 chunks per lane in chunkscan
#define PAD_PER 98                    // nodes padded per hist block
// scatter granularity (coarse, for long coalesced runs)
#define NCH_S   256
#define CH_S    (N_EDGES / NCH_S)     // 12500
#define BS1     1024                  // scatter1 block size
#define S2_CAP  2560                  // scatter2 LDS stage capacity
#define BLOCK   256
#define W_SCALE 32767.0f
#define W_INV   (1.0f / 32767.0f)

// ---------------------------------------------------------------------------
// Stage 1: per-subchunk bucket histogram + fused x->fp16 padding
// ---------------------------------------------------------------------------
__global__ void hist_kernel(const int* __restrict__ dst, int* __restrict__ hist_g,
                            const float* __restrict__ x, __half* __restrict__ xpad) {
    __shared__ int h[NB];
    for (int b = threadIdx.x; b < NB; b += BLOCK) h[b] = 0;
    {
        int i = blockIdx.x * PAD_PER + threadIdx.x;
        if (threadIdx.x < PAD_PER && i < N_NODES) {
            const float* xr = x + (size_t)i * 6;
            __half2 hh[4];
            hh[0] = __halves2half2(__float2half(xr[0]), __float2half(xr[1]));
            hh[1] = __halves2half2(__float2half(xr[2]), __float2half(xr[3]));
            hh[2] = __halves2half2(__float2half(xr[4]), __float2half(xr[5]));
            hh[3] = __halves2half2(__float2half(0.f),   __float2half(0.f));
            *(uint4*)(xpad + (size_t)i * 8) = *(uint4*)hh;
        }
    }
    __syncthreads();
    const int c  = blockIdx.x;
    const int k0 = c * CH_H;
    for (int k = threadIdx.x; k < CH_H; k += BLOCK)
        atomicAdd(&h[dst[k0 + k] >> 6], 1);
    __syncthreads();
    for (int b = threadIdx.x; b < NB; b += BLOCK)
        hist_g[c * NB + b] = h[b];
}

// ---------------------------------------------------------------------------
// Stage 2a: per-bucket exclusive scan over the 1024 subchunk counts
// ---------------------------------------------------------------------------
__global__ void chunkscan_kernel(const int* __restrict__ hist_g,
                                 int* __restrict__ off_g, int* __restrict__ tot) {
    int w    = (blockIdx.x * blockDim.x + threadIdx.x) >> 6;
    int lane = threadIdx.x & 63;
    if (w >= NB) return;
    int v[CPL];
    int ls = 0;
    const int cbase = lane * CPL;
    #pragma unroll
    for (int i = 0; i < CPL; ++i) { v[i] = hist_g[(cbase + i) * NB + w]; ls += v[i]; }
    int run = ls;
    #pragma unroll
    for (int d = 1; d < 64; d <<= 1) {
        int u = __shfl_up(run, d);
        if (lane >= d) run += u;
    }
    int acc = run - ls;
    #pragma unroll
    for (int i = 0; i < CPL; ++i) { off_g[(cbase + i) * NB + w] = acc; acc += v[i]; }
    if (lane == 63) tot[w] = acc;
}

// ---------------------------------------------------------------------------
// Stage 2b: exclusive scan of 1563 bucket totals (one wg)
// ---------------------------------------------------------------------------
#define SCAN_T   1024
#define SCAN_PER 2
__global__ void scan_kernel(const int* __restrict__ cnt, int* __restrict__ bstart) {
    __shared__ int part[SCAN_T];
    int t = threadIdx.x;
    int local[SCAN_PER];
    int s = 0;
    #pragma unroll
    for (int i = 0; i < SCAN_PER; ++i) {
        int idx = t * SCAN_PER + i;
        int v = (idx < NB) ? cnt[idx] : 0;
        local[i] = s;
        s += v;
    }
    part[t] = s;
    __syncthreads();
    for (int off = 1; off < SCAN_T; off <<= 1) {
        int v = (t >= off) ? part[t - off] : 0;
        __syncthreads();
        part[t] += v;
        __syncthreads();
    }
    int excl = part[t] - s;
    #pragma unroll
    for (int i = 0; i < SCAN_PER; ++i) {
        int idx = t * SCAN_PER + i;
        if (idx < NB) bstart[idx] = excl + local[i];
    }
}

// ---------------------------------------------------------------------------
// Stage 3: scatter pass 1, stage-and-flush. Chunk-local bucket counts come
// from off_g row diffs (hist_kernel already counted) — no histogram pass.
// rec1: x = src(17) | dl(6)<<17 ; y = weight fp32 bits.
// ---------------------------------------------------------------------------
__global__ void __launch_bounds__(BS1)
scatter1_kernel(const int* __restrict__ src, const int* __restrict__ dst,
                const float* __restrict__ w,
                const int* __restrict__ bstart, const int* __restrict__ off_g,
                const int* __restrict__ tot,
                uint2* __restrict__ rec1) {
    __shared__ uint32_t stage[CH_S];   // 50000 B
    __shared__ int h[NB];              // cursor (stage offset)
    __shared__ int delta[NB];          // flush addr = delta[b] + stage_idx
    __shared__ int wtot[BS1 / 64];

    const int c  = blockIdx.x;
    const int k0 = c * CH_S;
    const int t  = threadIdx.x;

    // phase A: chunk-local counts from off_g diffs; block scan -> cursors
    {
        const int base = t * 2;          // 2048 >= NB
        int v[2], lo[2], ls = 0;
        #pragma unroll
        for (int i = 0; i < 2; ++i) {
            int idx = base + i;
            if (idx < NB) {
                lo[i] = off_g[(size_t)(4 * c) * NB + idx];
                int hi = (c == NCH_S - 1) ? tot[idx]
                                          : off_g[(size_t)(4 * c + 4) * NB + idx];
                v[i] = hi - lo[i];
            } else { v[i] = 0; lo[i] = 0; }
            ls += v[i];
        }
        int lane = t & 63, wv = t >> 6;
        int run = ls;
        #pragma unroll
        for (int d = 1; d < 64; d <<= 1) {
            int u = __shfl_up(run, d);
            if (lane >= d) run += u;
        }
        if (lane == 63) wtot[wv] = run;
        __syncthreads();
        int wexcl = 0;
        for (int i = 0; i < wv; ++i) wexcl += wtot[i];
        int excl = wexcl + run - ls;
        #pragma unroll
        for (int i = 0; i < 2; ++i) {
            int idx = base + i;
            if (idx < NB) {
                h[idx]     = excl;
                delta[idx] = bstart[idx] + lo[i] - excl;
                excl += v[i];
            }
        }
    }
    __syncthreads();

    // phase B: read dst once, scatter packed tokens into stage (LDS cursors)
    // token = le(14) | dl(6)<<14 | b(11)<<20
    for (int k = t; k < CH_S; k += BS1) {
        int d = dst[k0 + k];
        int b = d >> 6;
        int pos = atomicAdd(&h[b], 1);
        stage[pos] = (uint32_t)k | ((uint32_t)(d & 63) << 14) | ((uint32_t)b << 20);
    }
    __syncthreads();

    // phase C: flush in stage order -> lane-contiguous full-line stores
    for (int i = t; i < CH_S; i += BS1) {
        uint32_t sv = stage[i];
        int le = sv & 0x3FFF;
        int dl = (sv >> 14) & 0x3F;
        int b  = sv >> 20;
        int e  = k0 + le;
        uint2 r;
        r.x = (uint32_t)src[e] | ((uint32_t)dl << 17);
        r.y = __float_as_uint(w[e]);
        rec1[delta[b] + i] = r;
    }
}

// ---------------------------------------------------------------------------
// Stage 4: scatter pass 2 — node-sort each bucket. rec1 read from HBM once
// (LDS cache); sort + flush from/to LDS. rec2 = src(17) | w15(15)<<17.
// ---------------------------------------------------------------------------
__global__ void scatter2_kernel(const uint2* __restrict__ rec1,
                                const int* __restrict__ bstart, const int* __restrict__ tot,
                                uint32_t* __restrict__ rec2,
                                int* __restrict__ row_start, int* __restrict__ cnt) {
    __shared__ int h[BN];
    __shared__ int cur[BN];
    __shared__ uint2 sin[S2_CAP];        // 20.5 KB read-once cache
    __shared__ uint32_t sout[S2_CAP];    // 10.2 KB sorted output stage
    const int b  = blockIdx.x;
    const int s0 = bstart[b];
    const int n  = tot[b];
    if (threadIdx.x < BN) h[threadIdx.x] = 0;
    __syncthreads();
    for (int k = threadIdx.x; k < n; k += BLOCK) {
        uint2 r = rec1[s0 + k];
        if (k < S2_CAP) sin[k] = r;
        atomicAdd(&h[r.x >> 17], 1);
    }
    __syncthreads();
    if (threadIdx.x < BN) {
        int v = h[threadIdx.x];
        int run = v;
        #pragma unroll
        for (int d = 1; d < 64; d <<= 1) {
            int u = __shfl_up(run, d);
            if (threadIdx.x >= d) run += u;
        }
        int excl = run - v;
        cur[threadIdx.x] = excl;
        int node = b * BN + threadIdx.x;
        if (node < N_NODES) { row_start[node] = s0 + excl; cnt[node] = v; }
    }
    __syncthreads();
    for (int k = threadIdx.x; k < n; k += BLOCK) {
        uint2 r = (k < S2_CAP) ? sin[k] : rec1[s0 + k];
        int dl = (int)(r.x >> 17);
        float wv = __uint_as_float(r.y);
        uint32_t w15 = (uint32_t)__float2uint_rn(wv * W_SCALE);
        uint32_t r2 = (r.x & 0x1FFFF) | (w15 << 17);
        int pos = atomicAdd(&cur[dl], 1);
        if (pos < S2_CAP) sout[pos] = r2;
        else              rec2[s0 + pos] = r2;
    }
    __syncthreads();
    for (int i = threadIdx.x; i < n && i < S2_CAP; i += BLOCK)
        rec2[s0 + i] = sout[i];
}

// ---------------------------------------------------------------------------
// Layer 0 fused (8 lanes/node, 4-deep batching — R9-proven): aggregate xpad,
// relu, emit p1 (fp16) + oinit1.
// ---------------------------------------------------------------------------
__global__ void layer0_kernel(const __half* __restrict__ xpad,
                              const uint32_t* __restrict__ rec,
                              const int* __restrict__ row_start, const int* __restrict__ cnt,
                              const float* __restrict__ wrel0, const float* __restrict__ brel0,
                              const float* __restrict__ wroot0,
                              const float* __restrict__ wrel1, const float* __restrict__ brel1,
                              const float* __restrict__ wroot1,
                              __half* __restrict__ pn, float* __restrict__ oinitn) {
    __shared__ float s_wrel0[6 * 20], s_wroot0[6 * 20], s_b0[20];
    __shared__ float s_wrel1[20 * 15], s_wroot1[20 * 15], s_b1[15];
    for (int t = threadIdx.x; t < 120; t += BLOCK) {
        s_wrel0[t]  = wrel0[t];
        s_wroot0[t] = wroot0[t];
    }
    for (int t = threadIdx.x; t < 300; t += BLOCK) {
        s_wrel1[t]  = wrel1[t];
        s_wroot1[t] = wroot1[t];
    }
    if (threadIdx.x < 20) s_b0[threadIdx.x] = brel0[threadIdx.x];
    if (threadIdx.x < 15) s_b1[threadIdx.x] = brel1[threadIdx.x];
    __syncthreads();

    int t = blockIdx.x * blockDim.x + threadIdx.x;
    int node = t >> 3;
    int q    = t & 7;

    float agg[6] = {0.f, 0.f, 0.f, 0.f, 0.f, 0.f};
    const int s = row_start[node];
    const int e = s + cnt[node];
    for (int k = s + q; k < e; k += 32) {
        uint32_t rv[4];
        float    wv[4];
        #pragma unroll
        for (int u = 0; u < 4; ++u) {
            int kk = k + 8 * u;
            int kc = kk < e ? kk : (e - 1);
            rv[u] = rec[kc];
            wv[u] = kk < e ? (float)(rv[u] >> 17) * W_INV : 0.f;
        }
        uint4 raw[4];
        #pragma unroll
        for (int u = 0; u < 4; ++u)
            raw[u] = *(const uint4*)(xpad + (size_t)(rv[u] & 0x1FFFF) * 8);
        #pragma unroll
        for (int u = 0; u < 4; ++u) {
            const __half2* h = (const __half2*)&raw[u];
            float w = wv[u];
            agg[0] += w * __low2float(h[0]);  agg[1] += w * __high2float(h[0]);
            agg[2] += w * __low2float(h[1]);  agg[3] += w * __high2float(h[1]);
            agg[4] += w * __low2float(h[2]);  agg[5] += w * __high2float(h[2]);
        }
    }
    #pragma unroll
    for (int i = 0; i < 6; ++i) {
        agg[i] += __shfl_xor(agg[i], 1);
        agg[i] += __shfl_xor(agg[i], 2);
        agg[i] += __shfl_xor(agg[i], 4);
    }
    uint4 raws = *(const uint4*)(xpad + (size_t)node * 8);
    const __half2* hs = (const __half2*)&raws;
    float xv[6] = { __low2float(hs[0]), __high2float(hs[0]),
                    __low2float(hs[1]), __high2float(hs[1]),
                    __low2float(hs[2]), __high2float(hs[2]) };
    float ov[20];
    #pragma unroll
    for (int j = 0; j < 20; ++j) {
        float o = s_b0[j];
        #pragma unroll
        for (int i = 0; i < 6; ++i)
            o += agg[i] * s_wrel0[i * 20 + j] + xv[i] * s_wroot0[i * 20 + j];
        ov[j] = fmaxf(o, 0.f);
    }
    {
        float pk[2] = {0.f, 0.f};
        #pragma unroll
        for (int kk = 0; kk < 2; ++kk) {
            int k = 2 * q + kk;
            if (k < 15) {
                float sacc = 0.f;
                #pragma unroll
                for (int j = 0; j < 20; ++j) sacc += ov[j] * s_wrel1[j * 15 + k];
                pk[kk] = sacc;
            }
        }
        ((__half2*)(pn + (size_t)node * 16))[q] =
            __halves2half2(__float2half(pk[0]), __float2half(pk[1]));
    }
    #pragma unroll
    for (int kk = 0; kk < 2; ++kk) {
        int k = q + kk * 8;
        if (k < 15) {
            float sacc = s_b1[k];
            #pragma unroll
            for (int j = 0; j < 20; ++j) sacc += ov[j] * s_wroot1[j * 15 + k];
            oinitn[(size_t)node * 15 + k] = sacc;
        }
    }
}

// ---------------------------------------------------------------------------
// Fused gather layer (8 lanes/node, 4-deep batching — R9-proven): aggregate
// p_i, relu + oinit_i, emit p_{i+1} + oinit_{i+1}. LAST: softmax.
// ---------------------------------------------------------------------------
template<int DOUT, int SPH, int NDOUT, int NSPH, bool LAST>
__global__ void gather_kernel(const __half* __restrict__ p, const float* __restrict__ oinit,
                              const uint32_t* __restrict__ rec,
                              const int* __restrict__ row_start, const int* __restrict__ cnt,
                              const float* __restrict__ wrel_n, const float* __restrict__ brel_n,
                              const float* __restrict__ wroot_n,
                              __half* __restrict__ pn, float* __restrict__ oinitn,
                              float* __restrict__ out) {
    __shared__ float s_wrel[LAST ? 1 : DOUT * NDOUT];
    __shared__ float s_wroot[LAST ? 1 : DOUT * NDOUT];
    __shared__ float s_b[LAST ? 1 : (NDOUT > 0 ? NDOUT : 1)];
    if constexpr (!LAST) {
        for (int t = threadIdx.x; t < DOUT * NDOUT; t += BLOCK) {
            s_wrel[t]  = wrel_n[t];
            s_wroot[t] = wroot_n[t];
        }
        if (threadIdx.x < NDOUT) s_b[threadIdx.x] = brel_n[threadIdx.x];
        __syncthreads();
    }

    int t = blockIdx.x * blockDim.x + threadIdx.x;
    int node = t >> 3;
    int q    = t & 7;

    float af[SPH];
    #pragma unroll
    for (int i = 0; i < SPH; ++i) af[i] = 0.f;

    const int s = row_start[node];
    const int e = s + cnt[node];
    constexpr int NR = (SPH >= 8) ? SPH / 8 : 1;
    for (int k = s + q; k < e; k += 32) {
        uint32_t rv[4];
        float    wv[4];
        #pragma unroll
        for (int u = 0; u < 4; ++u) {
            int kk = k + 8 * u;
            int kc = kk < e ? kk : (e - 1);
            rv[u] = rec[kc];
            wv[u] = kk < e ? (float)(rv[u] >> 17) * W_INV : 0.f;
        }
        if constexpr (SPH >= 8) {
            uint4 raw[4 * NR];
            #pragma unroll
            for (int u = 0; u < 4; ++u) {
                const uint4* ps = (const uint4*)(p + (size_t)(rv[u] & 0x1FFFF) * SPH);
                #pragma unroll
                for (int v = 0; v < NR; ++v) raw[u * NR + v] = ps[v];
            }
            #pragma unroll
            for (int u = 0; u < 4; ++u) {
                float w = wv[u];
                #pragma unroll
                for (int v = 0; v < NR; ++v) {
                    const __half2* h = (const __half2*)&raw[u * NR + v];
                    #pragma unroll
                    for (int jj = 0; jj < 4; ++jj) {
                        af[v * 8 + 2 * jj]     += w * __low2float(h[jj]);
                        af[v * 8 + 2 * jj + 1] += w * __high2float(h[jj]);
                    }
                }
            }
        } else {
            uint32_t raw[4];
            #pragma unroll
            for (int u = 0; u < 4; ++u)
                raw[u] = *(const uint32_t*)(p + (size_t)(rv[u] & 0x1FFFF) * SPH);
            #pragma unroll
            for (int u = 0; u < 4; ++u) {
                __half2 h = *(const __half2*)&raw[u];
                af[0] += wv[u] * __low2float(h);
                af[1] += wv[u] * __high2float(h);
            }
        }
    }
    #pragma unroll
    for (int i = 0; i < SPH; ++i) {
        af[i] += __shfl_xor(af[i], 1);
        af[i] += __shfl_xor(af[i], 2);
        af[i] += __shfl_xor(af[i], 4);
    }

    if constexpr (LAST) {
        if (q == 0) {
            float o0 = af[0] + oinit[(size_t)node * 2 + 0];
            float o1 = af[1] + oinit[(size_t)node * 2 + 1];
            float m = fmaxf(o0, o1);
            float e0 = __expf(o0 - m), e1 = __expf(o1 - m);
            float inv = 1.f / (e0 + e1);
            out[(size_t)node * 2 + 0] = e0 * inv;
            out[(size_t)node * 2 + 1] = e1 * inv;
        }
    } else {
        float ov[DOUT];
        #pragma unroll
        for (int j = 0; j < DOUT; ++j)
            ov[j] = fmaxf(af[j] + oinit[(size_t)node * DOUT + j], 0.f);

        if (q < NSPH / 2) {
            float pk[2] = {0.f, 0.f};
            #pragma unroll
            for (int kk = 0; kk < 2; ++kk) {
                int k = 2 * q + kk;
                if (k < NDOUT) {
                    float sacc = 0.f;
                    #pragma unroll
                    for (int j = 0; j < DOUT; ++j) sacc += ov[j] * s_wrel[j * NDOUT + k];
                    pk[kk] = sacc;
                }
            }
            ((__half2*)(pn + (size_t)node * NSPH))[q] =
                __halves2half2(__float2half(pk[0]), __float2half(pk[1]));
        }
        #pragma unroll
        for (int kk = 0; kk < 2; ++kk) {
            int k = q + kk * 8;
            if (k < NDOUT) {
                float sacc = s_b[k];
                #pragma unroll
                for (int j = 0; j < DOUT; ++j) sacc += ov[j] * s_wroot[j * NDOUT + k];
                oinitn[(size_t)node * NDOUT + k] = sacc;
            }
        }
    }
}

// ---------------------------------------------------------------------------

extern "C" void kernel_launch(void* const* d_in, const int* in_sizes, int n_in,
                              void* d_out, int out_size, void* d_ws, size_t ws_size,
                              hipStream_t stream) {
    const float* x  = (const float*)d_in[0];
    const int*   ei = (const int*)d_in[1];
    const float* ew = (const float*)d_in[2];
    const float* wrel[5]  = { (const float*)d_in[3], (const float*)d_in[6],
                              (const float*)d_in[9], (const float*)d_in[12],
                              (const float*)d_in[15] };
    const float* brel[5]  = { (const float*)d_in[4], (const float*)d_in[7],
                              (const float*)d_in[10], (const float*)d_in[13],
                              (const float*)d_in[16] };
    const float* wroot[5] = { (const float*)d_in[5], (const float*)d_in[8],
                              (const float*)d_in[11], (const float*)d_in[14],
                              (const float*)d_in[17] };

    char* ws = (char*)d_ws;
    size_t off = 0;
    auto alloc = [&](size_t bytes) -> void* {
        void* ptr = ws + off;
        off += (bytes + 255) & ~(size_t)255;
        return ptr;
    };
    // regionA: rec1 during sort (25.6 MB); p/oinit ping-pong during layers
    char*     regionA   = (char*)alloc((size_t)N_EDGES * 8);
    uint2*    rec1      = (uint2*)regionA;
    __half*   pA        = (__half*)regionA;                              // 3.2 MB
    __half*   pB        = (__half*)(regionA + (size_t)4  * 1024 * 1024); // 3.2 MB
    float*    oA        = (float*)(regionA + (size_t)8  * 1024 * 1024);  // 6 MB
    float*    oB        = (float*)(regionA + (size_t)16 * 1024 * 1024);  // 6 MB
    uint32_t* rec2      = (uint32_t*)alloc((size_t)N_EDGES * 4);         // 12.8 MB
    __half*   xpad      = (__half*)alloc((size_t)N_NODES * 8 * 2);       // 1.6 MB
    int*      hist_g    = (int*)alloc((size_t)NCH_H * NB * 4);           // 6.4 MB
    int*      off_g     = (int*)alloc((size_t)NCH_H * NB * 4);           // 6.4 MB
    int*      tot       = (int*)alloc((size_t)NB * 4);
    int*      bstart    = (int*)alloc((size_t)NB * 4);
    int*      row_start = (int*)alloc((size_t)N_NODES * 4);
    int*      cntb      = (int*)alloc((size_t)N_NODES * 4);

    const int* srcv = ei;            // edge_index row 0
    const int* dstv = ei + N_EDGES;  // edge_index row 1

    const int gN8 = (8 * N_NODES + BLOCK - 1) / BLOCK;      // 3125

    hist_kernel     <<<NCH_H, BLOCK, 0, stream>>>(dstv, hist_g, x, xpad);
    chunkscan_kernel<<<(NB + 3) / 4, BLOCK, 0, stream>>>(hist_g, off_g, tot);
    scan_kernel     <<<1, SCAN_T, 0, stream>>>(tot, bstart);
    scatter1_kernel <<<NCH_S, BS1, 0, stream>>>(srcv, dstv, ew, bstart, off_g, tot, rec1);
    scatter2_kernel <<<NB, BLOCK, 0, stream>>>(rec1, bstart, tot, rec2, row_start, cntb);

    // L0 fused: 6 -> 20 (relu) -> emit p1 [15, SPH 16] + oinit1
    layer0_kernel<<<gN8, BLOCK, 0, stream>>>(xpad, rec2, row_start, cntb,
                                             wrel[0], brel[0], wroot[0],
                                             wrel[1], brel[1], wroot[1], pA, oA);
    // g1: agg p1, out1 [15] -> p2 [10, SPH 16] + oinit2
    gather_kernel<15, 16, 10, 16, false><<<gN8, BLOCK, 0, stream>>>(
        pA, oA, rec2, row_start, cntb, wrel[2], brel[2], wroot[2], pB, oB, nullptr);
    // g2: agg p2, out2 [10] -> p3 [5, SPH 8] + oinit3
    gather_kernel<10, 16, 5, 8, false><<<gN8, BLOCK, 0, stream>>>(
        pB, oB, rec2, row_start, cntb, wrel[3], brel[3], wroot[3], pA, oA, nullptr);
    // g3: agg p3, out3 [5] -> p4 [2, SPH 2] + oinit4
    gather_kernel<5, 8, 2, 2, false><<<gN8, BLOCK, 0, stream>>>(
        pA, oA, rec2, row_start, cntb, wrel[4], brel[4], wroot[4], pB, oB, nullptr);
    // g4: agg p4, softmax -> d_out
    gather_kernel<2, 2, 0, 0, true><<<gN8, BLOCK, 0, stream>>>(
        pB, oB, rec2, row_start, cntb, nullptr, nullptr, nullptr,
        nullptr, nullptr, (float*)d_out);
}

// Round 14
// 320.652 us; speedup vs baseline: 3.1113x; 1.0245x over previous
//
#include <hip/hip_runtime.h>
#include <hip/hip_fp16.h>
#include <stdint.h>

#define N_NODES 100000
#define N_EDGES 3200000
#define BN      64                    // nodes per dst-bucket
#define NB      1563                  // ceil(N_NODES / BN)
// histogram granularity (fine)
#define NCH_H   1024
#define CH_H    (N_EDGES / NCH_H)     // 3125
#define CPL     (NCH_H / 64)          // 16 chunks per lane in chunkscan
#define PAD_PER 98                    // nodes padded per hist block
// scatter granularity (coarse, for long coalesced runs)
#define NCH_S   256
#define CH_S    (N_EDGES / NCH_S)     // 12500
#define BS1     1024                  // scatter1 block size
#define S1_IT   ((CH_S + BS1 - 1) / BS1)
#define S2_CAP  2560                  // scatter2 LDS stage capacity
#define BLOCK   256
#define W_SCALE 32767.0f
#define W_INV   (1.0f / 32767.0f)

// ---------------------------------------------------------------------------
// Stage 1: per-subchunk bucket histogram + fused x->fp16 padding
// ---------------------------------------------------------------------------
__global__ void hist_kernel(const int* __restrict__ dst, int* __restrict__ hist_g,
                            const float* __restrict__ x, __half* __restrict__ xpad) {
    __shared__ int h[NB];
    for (int b = threadIdx.x; b < NB; b += BLOCK) h[b] = 0;
    {
        int i = blockIdx.x * PAD_PER + threadIdx.x;
        if (threadIdx.x < PAD_PER && i < N_NODES) {
            const float* xr = x + (size_t)i * 6;
            __half2 hh[4];
            hh[0] = __halves2half2(__float2half(xr[0]), __float2half(xr[1]));
            hh[1] = __halves2half2(__float2half(xr[2]), __float2half(xr[3]));
            hh[2] = __halves2half2(__float2half(xr[4]), __float2half(xr[5]));
            hh[3] = __halves2half2(__float2half(0.f),   __float2half(0.f));
            *(uint4*)(xpad + (size_t)i * 8) = *(uint4*)hh;
        }
    }
    __syncthreads();
    const int c  = blockIdx.x;
    const int k0 = c * CH_H;
    for (int k = threadIdx.x; k < CH_H; k += BLOCK)
        atomicAdd(&h[dst[k0 + k] >> 6], 1);
    __syncthreads();
    for (int b = threadIdx.x; b < NB; b += BLOCK)
        hist_g[c * NB + b] = h[b];
}

// ---------------------------------------------------------------------------
// Stage 2a: per-bucket exclusive scan over the 1024 subchunk counts
// ---------------------------------------------------------------------------
__global__ void chunkscan_kernel(const int* __restrict__ hist_g,
                                 int* __restrict__ off_g, int* __restrict__ tot) {
    int w    = (blockIdx.x * blockDim.x + threadIdx.x) >> 6;
    int lane = threadIdx.x & 63;
    if (w >= NB) return;
    int v[CPL];
    int ls = 0;
    const int cbase = lane * CPL;
    #pragma unroll
    for (int i = 0; i < CPL; ++i) { v[i] = hist_g[(cbase + i) * NB + w]; ls += v[i]; }
    int run = ls;
    #pragma unroll
    for (int d = 1; d < 64; d <<= 1) {
        int u = __shfl_up(run, d);
        if (lane >= d) run += u;
    }
    int acc = run - ls;
    #pragma unroll
    for (int i = 0; i < CPL; ++i) { off_g[(cbase + i) * NB + w] = acc; acc += v[i]; }
    if (lane == 63) tot[w] = acc;
}

// ---------------------------------------------------------------------------
// Stage 2b: exclusive scan of 1563 bucket totals (one wg)
// ---------------------------------------------------------------------------
#define SCAN_T   1024
#define SCAN_PER 2
__global__ void scan_kernel(const int* __restrict__ cnt, int* __restrict__ bstart) {
    __shared__ int part[SCAN_T];
    int t = threadIdx.x;
    int local[SCAN_PER];
    int s = 0;
    #pragma unroll
    for (int i = 0; i < SCAN_PER; ++i) {
        int idx = t * SCAN_PER + i;
        int v = (idx < NB) ? cnt[idx] : 0;
        local[i] = s;
        s += v;
    }
    part[t] = s;
    __syncthreads();
    for (int off = 1; off < SCAN_T; off <<= 1) {
        int v = (t >= off) ? part[t - off] : 0;
        __syncthreads();
        part[t] += v;
        __syncthreads();
    }
    int excl = part[t] - s;
    #pragma unroll
    for (int i = 0; i < SCAN_PER; ++i) {
        int idx = t * SCAN_PER + i;
        if (idx < NB) bstart[idx] = excl + local[i];
    }
}

// ---------------------------------------------------------------------------
// Stage 3: scatter pass 1, stage-and-flush (R9-proven structure); flush
// phase now batched 4-deep to break the stage->src/w->store latency chain.
// rec1: x = src(17) | dl(6)<<17 ; y = weight fp32 bits.
// ---------------------------------------------------------------------------
__global__ void __launch_bounds__(BS1)
scatter1_kernel(const int* __restrict__ src, const int* __restrict__ dst,
                const float* __restrict__ w,
                const int* __restrict__ bstart, const int* __restrict__ off_g,
                uint2* __restrict__ rec1) {
    __shared__ uint32_t stage[CH_S];   // 50000 B
    __shared__ int h[NB];
    __shared__ int delta[NB];
    __shared__ int wtot[BS1 / 64];

    const int c  = blockIdx.x;
    const int k0 = c * CH_S;
    const int t  = threadIdx.x;

    // phase 1: histogram (cache dst in regs)
    for (int b = t; b < NB; b += BS1) h[b] = 0;
    __syncthreads();
    int dstv[S1_IT];
    int nit = 0;
    for (int k = t; k < CH_S; k += BS1, ++nit) {
        int d = dst[k0 + k];
        dstv[nit] = d;
        atomicAdd(&h[d >> 6], 1);
    }
    __syncthreads();

    // phase 2: block scan of h -> cursor start (in h) + delta
    {
        const int base = t * 2;          // 2048 >= NB
        int v[2], ls = 0;
        #pragma unroll
        for (int i = 0; i < 2; ++i) {
            int idx = base + i;
            v[i] = (idx < NB) ? h[idx] : 0;
            ls += v[i];
        }
        int lane = t & 63, wv = t >> 6;
        int run = ls;
        #pragma unroll
        for (int d = 1; d < 64; d <<= 1) {
            int u = __shfl_up(run, d);
            if (lane >= d) run += u;
        }
        if (lane == 63) wtot[wv] = run;
        __syncthreads();
        int wexcl = 0;
        for (int i = 0; i < wv; ++i) wexcl += wtot[i];
        int excl = wexcl + run - ls;
        #pragma unroll
        for (int i = 0; i < 2; ++i) {
            int idx = base + i;
            if (idx < NB) {
                int gb = bstart[idx] + off_g[(size_t)(4 * c) * NB + idx];
                h[idx]     = excl;
                delta[idx] = gb - excl;
                excl += v[i];
            }
        }
    }
    __syncthreads();

    // phase 3: scatter packed tokens into stage (LDS cursors)
    // token = le(14) | dl(6)<<14 | b(11)<<20
    nit = 0;
    for (int k = t; k < CH_S; k += BS1, ++nit) {
        int d = dstv[nit];
        int b = d >> 6;
        int pos = atomicAdd(&h[b], 1);
        stage[pos] = (uint32_t)k | ((uint32_t)(d & 63) << 14) | ((uint32_t)b << 20);
    }
    __syncthreads();

    // phase 4: flush in stage order, 4-deep batched:
    //   4 stage reads -> 8 independent src/w loads -> 4 stores
    for (int i = t; i < CH_S; i += 4 * BS1) {
        uint32_t sv[4];
        #pragma unroll
        for (int u = 0; u < 4; ++u) {
            int ii = i + u * BS1;
            sv[u] = (ii < CH_S) ? stage[ii] : 0u;
        }
        uint32_t ssrc[4], sw[4];
        #pragma unroll
        for (int u = 0; u < 4; ++u) {
            int e = k0 + (int)(sv[u] & 0x3FFF);
            ssrc[u] = (uint32_t)src[e];
            sw[u]   = __float_as_uint(w[e]);
        }
        #pragma unroll
        for (int u = 0; u < 4; ++u) {
            int ii = i + u * BS1;
            if (ii < CH_S) {
                uint2 r;
                r.x = ssrc[u] | (((sv[u] >> 14) & 0x3F) << 17);
                r.y = sw[u];
                rec1[delta[sv[u] >> 20] + ii] = r;
            }
        }
    }
}

// ---------------------------------------------------------------------------
// Stage 4: scatter pass 2 — node-sort each bucket through an LDS stage
// (R9-proven: second rec1 pass is L2-hit; small LDS keeps occupancy high).
// Emits 4 B rec2 = src(17) | w15(15)<<17.
// ---------------------------------------------------------------------------
__global__ void scatter2_kernel(const uint2* __restrict__ rec1,
                                const int* __restrict__ bstart, const int* __restrict__ tot,
                                uint32_t* __restrict__ rec2,
                                int* __restrict__ row_start, int* __restrict__ cnt) {
    __shared__ int h[BN];
    __shared__ int cur[BN];
    __shared__ uint32_t stage[S2_CAP];
    const int b  = blockIdx.x;
    const int s0 = bstart[b];
    const int n  = tot[b];
    if (threadIdx.x < BN) h[threadIdx.x] = 0;
    __syncthreads();
    for (int k = threadIdx.x; k < n; k += BLOCK)
        atomicAdd(&h[rec1[s0 + k].x >> 17], 1);
    __syncthreads();
    if (threadIdx.x < BN) {
        int v = h[threadIdx.x];
        int run = v;
        #pragma unroll
        for (int d = 1; d < 64; d <<= 1) {
            int u = __shfl_up(run, d);
            if (threadIdx.x >= d) run += u;
        }
        int excl = run - v;
        cur[threadIdx.x] = excl;
        int node = b * BN + threadIdx.x;
        if (node < N_NODES) { row_start[node] = s0 + excl; cnt[node] = v; }
    }
    __syncthreads();
    for (int k = threadIdx.x; k < n; k += BLOCK) {
        uint2 r = rec1[s0 + k];
        int dl = (int)(r.x >> 17);
        float wv = __uint_as_float(r.y);
        uint32_t w15 = (uint32_t)__float2uint_rn(wv * W_SCALE);
        uint32_t r2 = (r.x & 0x1FFFF) | (w15 << 17);
        int pos = atomicAdd(&cur[dl], 1);
        if (pos < S2_CAP) stage[pos] = r2;
        else              rec2[s0 + pos] = r2;
    }
    __syncthreads();
    for (int i = threadIdx.x; i < n && i < S2_CAP; i += BLOCK)
        rec2[s0 + i] = stage[i];
}

// ---------------------------------------------------------------------------
// Layer 0 fused (8 lanes/node, 4-deep batching — R9-proven): aggregate xpad,
// relu, emit p1 (fp16) + oinit1.
// ---------------------------------------------------------------------------
__global__ void layer0_kernel(const __half* __restrict__ xpad,
                              const uint32_t* __restrict__ rec,
                              const int* __restrict__ row_start, const int* __restrict__ cnt,
                              const float* __restrict__ wrel0, const float* __restrict__ brel0,
                              const float* __restrict__ wroot0,
                              const float* __restrict__ wrel1, const float* __restrict__ brel1,
                              const float* __restrict__ wroot1,
                              __half* __restrict__ pn, float* __restrict__ oinitn) {
    __shared__ float s_wrel0[6 * 20], s_wroot0[6 * 20], s_b0[20];
    __shared__ float s_wrel1[20 * 15], s_wroot1[20 * 15], s_b1[15];
    for (int t = threadIdx.x; t < 120; t += BLOCK) {
        s_wrel0[t]  = wrel0[t];
        s_wroot0[t] = wroot0[t];
    }
    for (int t = threadIdx.x; t < 300; t += BLOCK) {
        s_wrel1[t]  = wrel1[t];
        s_wroot1[t] = wroot1[t];
    }
    if (threadIdx.x < 20) s_b0[threadIdx.x] = brel0[threadIdx.x];
    if (threadIdx.x < 15) s_b1[threadIdx.x] = brel1[threadIdx.x];
    __syncthreads();

    int t = blockIdx.x * blockDim.x + threadIdx.x;
    int node = t >> 3;
    int q    = t & 7;

    float agg[6] = {0.f, 0.f, 0.f, 0.f, 0.f, 0.f};
    const int s = row_start[node];
    const int e = s + cnt[node];
    for (int k = s + q; k < e; k += 32) {
        uint32_t rv[4];
        float    wv[4];
        #pragma unroll
        for (int u = 0; u < 4; ++u) {
            int kk = k + 8 * u;
            int kc = kk < e ? kk : (e - 1);
            rv[u] = rec[kc];
            wv[u] = kk < e ? (float)(rv[u] >> 17) * W_INV : 0.f;
        }
        uint4 raw[4];
        #pragma unroll
        for (int u = 0; u < 4; ++u)
            raw[u] = *(const uint4*)(xpad + (size_t)(rv[u] & 0x1FFFF) * 8);
        #pragma unroll
        for (int u = 0; u < 4; ++u) {
            const __half2* h = (const __half2*)&raw[u];
            float w = wv[u];
            agg[0] += w * __low2float(h[0]);  agg[1] += w * __high2float(h[0]);
            agg[2] += w * __low2float(h[1]);  agg[3] += w * __high2float(h[1]);
            agg[4] += w * __low2float(h[2]);  agg[5] += w * __high2float(h[2]);
        }
    }
    #pragma unroll
    for (int i = 0; i < 6; ++i) {
        agg[i] += __shfl_xor(agg[i], 1);
        agg[i] += __shfl_xor(agg[i], 2);
        agg[i] += __shfl_xor(agg[i], 4);
    }
    uint4 raws = *(const uint4*)(xpad + (size_t)node * 8);
    const __half2* hs = (const __half2*)&raws;
    float xv[6] = { __low2float(hs[0]), __high2float(hs[0]),
                    __low2float(hs[1]), __high2float(hs[1]),
                    __low2float(hs[2]), __high2float(hs[2]) };
    float ov[20];
    #pragma unroll
    for (int j = 0; j < 20; ++j) {
        float o = s_b0[j];
        #pragma unroll
        for (int i = 0; i < 6; ++i)
            o += agg[i] * s_wrel0[i * 20 + j] + xv[i] * s_wroot0[i * 20 + j];
        ov[j] = fmaxf(o, 0.f);
    }
    {
        float pk[2] = {0.f, 0.f};
        #pragma unroll
        for (int kk = 0; kk < 2; ++kk) {
            int k = 2 * q + kk;
            if (k < 15) {
                float sacc = 0.f;
                #pragma unroll
                for (int j = 0; j < 20; ++j) sacc += ov[j] * s_wrel1[j * 15 + k];
                pk[kk] = sacc;
            }
        }
        ((__half2*)(pn + (size_t)node * 16))[q] =
            __halves2half2(__float2half(pk[0]), __float2half(pk[1]));
    }
    #pragma unroll
    for (int kk = 0; kk < 2; ++kk) {
        int k = q + kk * 8;
        if (k < 15) {
            float sacc = s_b1[k];
            #pragma unroll
            for (int j = 0; j < 20; ++j) sacc += ov[j] * s_wroot1[j * 15 + k];
            oinitn[(size_t)node * 15 + k] = sacc;
        }
    }
}

// ---------------------------------------------------------------------------
// Fused gather layer (8 lanes/node, 4-deep batching — R9-proven): aggregate
// p_i, relu + oinit_i, emit p_{i+1} + oinit_{i+1}. LAST: softmax.
// ---------------------------------------------------------------------------
template<int DOUT, int SPH, int NDOUT, int NSPH, bool LAST>
__global__ void gather_kernel(const __half* __restrict__ p, const float* __restrict__ oinit,
                              const uint32_t* __restrict__ rec,
                              const int* __restrict__ row_start, const int* __restrict__ cnt,
                              const float* __restrict__ wrel_n, const float* __restrict__ brel_n,
                              const float* __restrict__ wroot_n,
                              __half* __restrict__ pn, float* __restrict__ oinitn,
                              float* __restrict__ out) {
    __shared__ float s_wrel[LAST ? 1 : DOUT * NDOUT];
    __shared__ float s_wroot[LAST ? 1 : DOUT * NDOUT];
    __shared__ float s_b[LAST ? 1 : (NDOUT > 0 ? NDOUT : 1)];
    if constexpr (!LAST) {
        for (int t = threadIdx.x; t < DOUT * NDOUT; t += BLOCK) {
            s_wrel[t]  = wrel_n[t];
            s_wroot[t] = wroot_n[t];
        }
        if (threadIdx.x < NDOUT) s_b[threadIdx.x] = brel_n[threadIdx.x];
        __syncthreads();
    }

    int t = blockIdx.x * blockDim.x + threadIdx.x;
    int node = t >> 3;
    int q    = t & 7;

    float af[SPH];
    #pragma unroll
    for (int i = 0; i < SPH; ++i) af[i] = 0.f;

    const int s = row_start[node];
    const int e = s + cnt[node];
    constexpr int NR = (SPH >= 8) ? SPH / 8 : 1;
    for (int k = s + q; k < e; k += 32) {
        uint32_t rv[4];
        float    wv[4];
        #pragma unroll
        for (int u = 0; u < 4; ++u) {
            int kk = k + 8 * u;
            int kc = kk < e ? kk : (e - 1);
            rv[u] = rec[kc];
            wv[u] = kk < e ? (float)(rv[u] >> 17) * W_INV : 0.f;
        }
        if constexpr (SPH >= 8) {
            uint4 raw[4 * NR];
            #pragma unroll
            for (int u = 0; u < 4; ++u) {
                const uint4* ps = (const uint4*)(p + (size_t)(rv[u] & 0x1FFFF) * SPH);
                #pragma unroll
                for (int v = 0; v < NR; ++v) raw[u * NR + v] = ps[v];
            }
            #pragma unroll
            for (int u = 0; u < 4; ++u) {
                float w = wv[u];
                #pragma unroll
                for (int v = 0; v < NR; ++v) {
                    const __half2* h = (const __half2*)&raw[u * NR + v];
                    #pragma unroll
                    for (int jj = 0; jj < 4; ++jj) {
                        af[v * 8 + 2 * jj]     += w * __low2float(h[jj]);
                        af[v * 8 + 2 * jj + 1] += w * __high2float(h[jj]);
                    }
                }
            }
        } else {
            uint32_t raw[4];
            #pragma unroll
            for (int u = 0; u < 4; ++u)
                raw[u] = *(const uint32_t*)(p + (size_t)(rv[u] & 0x1FFFF) * SPH);
            #pragma unroll
            for (int u = 0; u < 4; ++u) {
                __half2 h = *(const __half2*)&raw[u];
                af[0] += wv[u] * __low2float(h);
                af[1] += wv[u] * __high2float(h);
            }
        }
    }
    #pragma unroll
    for (int i = 0; i < SPH; ++i) {
        af[i] += __shfl_xor(af[i], 1);
        af[i] += __shfl_xor(af[i], 2);
        af[i] += __shfl_xor(af[i], 4);
    }

    if constexpr (LAST) {
        if (q == 0) {
            float o0 = af[0] + oinit[(size_t)node * 2 + 0];
            float o1 = af[1] + oinit[(size_t)node * 2 + 1];
            float m = fmaxf(o0, o1);
            float e0 = __expf(o0 - m), e1 = __expf(o1 - m);
            float inv = 1.f / (e0 + e1);
            out[(size_t)node * 2 + 0] = e0 * inv;
            out[(size_t)node * 2 + 1] = e1 * inv;
        }
    } else {
        float ov[DOUT];
        #pragma unroll
        for (int j = 0; j < DOUT; ++j)
            ov[j] = fmaxf(af[j] + oinit[(size_t)node * DOUT + j], 0.f);

        if (q < NSPH / 2) {
            float pk[2] = {0.f, 0.f};
            #pragma unroll
            for (int kk = 0; kk < 2; ++kk) {
                int k = 2 * q + kk;
                if (k < NDOUT) {
                    float sacc = 0.f;
                    #pragma unroll
                    for (int j = 0; j < DOUT; ++j) sacc += ov[j] * s_wrel[j * NDOUT + k];
                    pk[kk] = sacc;
                }
            }
            ((__half2*)(pn + (size_t)node * NSPH))[q] =
                __halves2half2(__float2half(pk[0]), __float2half(pk[1]));
        }
        #pragma unroll
        for (int kk = 0; kk < 2; ++kk) {
            int k = q + kk * 8;
            if (k < NDOUT) {
                float sacc = s_b[k];
                #pragma unroll
                for (int j = 0; j < DOUT; ++j) sacc += ov[j] * s_wroot[j * NDOUT + k];
                oinitn[(size_t)node * NDOUT + k] = sacc;
            }
        }
    }
}

// ---------------------------------------------------------------------------

extern "C" void kernel_launch(void* const* d_in, const int* in_sizes, int n_in,
                              void* d_out, int out_size, void* d_ws, size_t ws_size,
                              hipStream_t stream) {
    const float* x  = (const float*)d_in[0];
    const int*   ei = (const int*)d_in[1];
    const float* ew = (const float*)d_in[2];
    const float* wrel[5]  = { (const float*)d_in[3], (const float*)d_in[6],
                              (const float*)d_in[9], (const float*)d_in[12],
                              (const float*)d_in[15] };
    const float* brel[5]  = { (const float*)d_in[4], (const float*)d_in[7],
                              (const float*)d_in[10], (const float*)d_in[13],
                              (const float*)d_in[16] };
    const float* wroot[5] = { (const float*)d_in[5], (const float*)d_in[8],
                              (const float*)d_in[11], (const float*)d_in[14],
                              (const float*)d_in[17] };

    char* ws = (char*)d_ws;
    size_t off = 0;
    auto alloc = [&](size_t bytes) -> void* {
        void* ptr = ws + off;
        off += (bytes + 255) & ~(size_t)255;
        return ptr;
    };
    // regionA: rec1 during sort (25.6 MB); p/oinit ping-pong during layers
    char*     regionA   = (char*)alloc((size_t)N_EDGES * 8);
    uint2*    rec1      = (uint2*)regionA;
    __half*   pA        = (__half*)regionA;                              // 3.2 MB
    __half*   pB        = (__half*)(regionA + (size_t)4  * 1024 * 1024); // 3.2 MB
    float*    oA        = (float*)(regionA + (size_t)8  * 1024 * 1024);  // 6 MB
    float*    oB        = (float*)(regionA + (size_t)16 * 1024 * 1024);  // 6 MB
    uint32_t* rec2      = (uint32_t*)alloc((size_t)N_EDGES * 4);         // 12.8 MB
    __half*   xpad      = (__half*)alloc((size_t)N_NODES * 8 * 2);       // 1.6 MB
    int*      hist_g    = (int*)alloc((size_t)NCH_H * NB * 4);           // 6.4 MB
    int*      off_g     = (int*)alloc((size_t)NCH_H * NB * 4);           // 6.4 MB
    int*      tot       = (int*)alloc((size_t)NB * 4);
    int*      bstart    = (int*)alloc((size_t)NB * 4);
    int*      row_start = (int*)alloc((size_t)N_NODES * 4);
    int*      cntb      = (int*)alloc((size_t)N_NODES * 4);

    const int* srcv = ei;            // edge_index row 0
    const int* dstv = ei + N_EDGES;  // edge_index row 1

    const int gN8 = (8 * N_NODES + BLOCK - 1) / BLOCK;      // 3125

    hist_kernel     <<<NCH_H, BLOCK, 0, stream>>>(dstv, hist_g, x, xpad);
    chunkscan_kernel<<<(NB + 3) / 4, BLOCK, 0, stream>>>(hist_g, off_g, tot);
    scan_kernel     <<<1, SCAN_T, 0, stream>>>(tot, bstart);
    scatter1_kernel <<<NCH_S, BS1, 0, stream>>>(srcv, dstv, ew, bstart, off_g, rec1);
    scatter2_kernel <<<NB, BLOCK, 0, stream>>>(rec1, bstart, tot, rec2, row_start, cntb);

    // L0 fused: 6 -> 20 (relu) -> emit p1 [15, SPH 16] + oinit1
    layer0_kernel<<<gN8, BLOCK, 0, stream>>>(xpad, rec2, row_start, cntb,
                                             wrel[0], brel[0], wroot[0],
                                             wrel[1], brel[1], wroot[1], pA, oA);
    // g1: agg p1, out1 [15] -> p2 [10, SPH 16] + oinit2
    gather_kernel<15, 16, 10, 16, false><<<gN8, BLOCK, 0, stream>>>(
        pA, oA, rec2, row_start, cntb, wrel[2], brel[2], wroot[2], pB, oB, nullptr);
    // g2: agg p2, out2 [10] -> p3 [5, SPH 8] + oinit3
    gather_kernel<10, 16, 5, 8, false><<<gN8, BLOCK, 0, stream>>>(
        pB, oB, rec2, row_start, cntb, wrel[3], brel[3], wroot[3], pA, oA, nullptr);
    // g3: agg p3, out3 [5] -> p4 [2, SPH 2] + oinit4
    gather_kernel<5, 8, 2, 2, false><<<gN8, BLOCK, 0, stream>>>(
        pA, oA, rec2, row_start, cntb, wrel[4], brel[4], wroot[4], pB, oB, nullptr);
    // g4: agg p4, softmax -> d_out
    gather_kernel<2, 2, 0, 0, true><<<gN8, BLOCK, 0, stream>>>(
        pB, oB, rec2, row_start, cntb, nullptr, nullptr, nullptr,
        nullptr, nullptr, (float*)d_out);
}